// Round 7
// baseline (4841.447 us; speedup 1.0000x reference)
//
#include <hip/hip_runtime.h>

// ---------------- problem constants ----------------
// B=32, T=250, FEAT=128, CLASSES=25, UNITS=512, CELL=64, HEADS=4, IN_LSTM=409

// ---------------- scratch layout (floats) ----------------
// All inter-block activations are (value,epoch) PAIRS (8 B, stored atomically).
constexpr size_t OFF_FEATP  = 0;                              // [8000][128]
constexpr size_t OFF_WXI    = OFF_FEATP + (size_t)8000 * 128; // [409][2048] gate-interleaved
constexpr size_t OFF_WHI    = OFF_WXI + (size_t)409 * 2048;   // [512][2048]
constexpr size_t OFF_BLI    = OFF_WHI + (size_t)512 * 2048;   // [2048]
constexpr size_t OFF_ZP2A   = OFF_BLI + 2048;                 // [2][32][2048]p (k-half 0 + bias/label)
constexpr size_t OFF_ZP2B   = OFF_ZP2A + 262144;              // [2][32][2048]p (k-half 1)
constexpr size_t OFF_OH2A   = OFF_ZP2B + 262144;              // [2][32][512]p
constexpr size_t OFF_OH2B   = OFF_OH2A + 65536;               // [2][32][512]p
constexpr size_t OFF_OUTPRE2= OFF_OH2B + 65536;               // [32][512]p
constexpr size_t OFF_HT2    = OFF_OUTPRE2 + 32768;            // [2][512][32]p
constexpr size_t OFF_HTT2   = OFF_HT2 + 65536;                // [2][32][512]p
constexpr size_t OFF_RVT2   = OFF_HTT2 + 65536;               // [2][256][32]p
constexpr size_t OFF_WVP2   = OFF_RVT2 + 32768;               // [2][2][32][64]p
constexpr size_t OFF_BAR    = OFF_WVP2 + 16384;               // counters (4096 ints)
constexpr size_t OFF_WPT    = OFF_BAR + 4096;                 // [128][320][4] k-major Wp
constexpr size_t WS_FLOATS  = OFF_WPT + (size_t)163840;

constexpr int DYN_FLOATS = 34816;                 // 136 KB dynamic LDS
constexpr int DYN_BYTES  = DYN_FLOATS * 4;

// WAR-slack counters only (8 lines x 64-int stride each). RAW sync is via tags.
constexpr int COH = 0, COP = 512, CCO = 1024, CRING = 1536;

__device__ __forceinline__ float sigm(float x) { return 1.f / (1.f + __expf(-x)); }

typedef int iv2 __attribute__((ext_vector_type(2)));
typedef int iv4 __attribute__((ext_vector_type(4)));
typedef float fv4 __attribute__((ext_vector_type(4)));

// ---- LLC-coherent accesses (bypass L1+L2). Batched loads with the waitcnt
// inside the asm so they are one round trip.
__device__ __forceinline__ void st_pair(float* base, size_t pidx, float v, int tag) {
  unsigned long long u = (unsigned long long)__float_as_uint(v) |
                         ((unsigned long long)(unsigned)tag << 32);
  __hip_atomic_store((unsigned long long*)(base + 2 * pidx), u,
                     __ATOMIC_RELAXED, __HIP_MEMORY_SCOPE_AGENT);
}
// two pairs at separate addresses
__device__ __forceinline__ float2 spin_pair_2addr(const float* a, const float* b, int tag) {
  const iv2* pa = (const iv2*)a;
  const iv2* pb = (const iv2*)b;
  iv2 x, y;
  for (;;) {
    asm volatile(
        "global_load_dwordx2 %0, %2, off sc0 sc1\n\t"
        "global_load_dwordx2 %1, %3, off sc0 sc1\n\t"
        "s_waitcnt vmcnt(0)"
        : "=&v"(x), "=&v"(y) : "v"(pa), "v"(pb) : "memory");
    if (x[1] == tag && y[1] == tag) break;
    __builtin_amdgcn_s_sleep(1);
  }
  return {__int_as_float(x[0]), __int_as_float(y[0])};
}
// four pairs at separate addresses (COUT quad spin)
__device__ __forceinline__ void ld4x2_sc(const iv2* a, const iv2* b, const iv2* c,
                                         const iv2* d, iv2& x, iv2& y, iv2& z, iv2& w) {
  asm volatile(
      "global_load_dwordx2 %0, %4, off sc0 sc1\n\t"
      "global_load_dwordx2 %1, %5, off sc0 sc1\n\t"
      "global_load_dwordx2 %2, %6, off sc0 sc1\n\t"
      "global_load_dwordx2 %3, %7, off sc0 sc1\n\t"
      "s_waitcnt vmcnt(0)"
      : "=&v"(x), "=&v"(y), "=&v"(z), "=&v"(w)
      : "v"(a), "v"(b), "v"(c), "v"(d) : "memory");
}
__device__ __forceinline__ void ld8i4_sc(const iv4* b0, iv4* v) {
  const iv4 *p0 = b0, *p1 = b0 + 512, *p2 = b0 + 1024, *p3 = b0 + 1536,
            *p4 = b0 + 2048, *p5 = b0 + 2560, *p6 = b0 + 3072, *p7 = b0 + 3584;
  asm volatile(
      "global_load_dwordx4 %0, %8, off sc0 sc1\n\t"
      "global_load_dwordx4 %1, %9, off sc0 sc1\n\t"
      "global_load_dwordx4 %2, %10, off sc0 sc1\n\t"
      "global_load_dwordx4 %3, %11, off sc0 sc1\n\t"
      "global_load_dwordx4 %4, %12, off sc0 sc1\n\t"
      "global_load_dwordx4 %5, %13, off sc0 sc1\n\t"
      "global_load_dwordx4 %6, %14, off sc0 sc1\n\t"
      "global_load_dwordx4 %7, %15, off sc0 sc1\n\t"
      "s_waitcnt vmcnt(0)"
      : "=&v"(v[0]), "=&v"(v[1]), "=&v"(v[2]), "=&v"(v[3]),
        "=&v"(v[4]), "=&v"(v[5]), "=&v"(v[6]), "=&v"(v[7])
      : "v"(p0), "v"(p1), "v"(p2), "v"(p3), "v"(p4), "v"(p5), "v"(p6), "v"(p7)
      : "memory");
}
// 8 strided dwordx4 (rv) + 2 dwordx4 at free addresses, one waitcnt
__device__ __forceinline__ void ld10i4_sc(const iv4* b0, const iv4* z0,
                                          const iv4* z1, iv4* v) {
  const iv4 *p0 = b0, *p1 = b0 + 512, *p2 = b0 + 1024, *p3 = b0 + 1536,
            *p4 = b0 + 2048, *p5 = b0 + 2560, *p6 = b0 + 3072, *p7 = b0 + 3584;
  asm volatile(
      "global_load_dwordx4 %0, %10, off sc0 sc1\n\t"
      "global_load_dwordx4 %1, %11, off sc0 sc1\n\t"
      "global_load_dwordx4 %2, %12, off sc0 sc1\n\t"
      "global_load_dwordx4 %3, %13, off sc0 sc1\n\t"
      "global_load_dwordx4 %4, %14, off sc0 sc1\n\t"
      "global_load_dwordx4 %5, %15, off sc0 sc1\n\t"
      "global_load_dwordx4 %6, %16, off sc0 sc1\n\t"
      "global_load_dwordx4 %7, %17, off sc0 sc1\n\t"
      "global_load_dwordx4 %8, %18, off sc0 sc1\n\t"
      "global_load_dwordx4 %9, %19, off sc0 sc1\n\t"
      "s_waitcnt vmcnt(0)"
      : "=&v"(v[0]), "=&v"(v[1]), "=&v"(v[2]), "=&v"(v[3]), "=&v"(v[4]),
        "=&v"(v[5]), "=&v"(v[6]), "=&v"(v[7]), "=&v"(v[8]), "=&v"(v[9])
      : "v"(p0), "v"(p1), "v"(p2), "v"(p3), "v"(p4), "v"(p5), "v"(p6), "v"(p7),
        "v"(z0), "v"(z1)
      : "memory");
}
// 4 contiguous dwordx4 (ATT per-lane h spin)
__device__ __forceinline__ void ld4i4o_sc(const iv4* b0, iv4& a, iv4& b,
                                          iv4& c, iv4& d) {
  asm volatile(
      "global_load_dwordx4 %0, %4, off sc0 sc1\n\t"
      "global_load_dwordx4 %1, %4, off offset:16 sc0 sc1\n\t"
      "global_load_dwordx4 %2, %4, off offset:32 sc0 sc1\n\t"
      "global_load_dwordx4 %3, %4, off offset:48 sc0 sc1\n\t"
      "s_waitcnt vmcnt(0)"
      : "=&v"(a), "=&v"(b), "=&v"(c), "=&v"(d) : "v"(b0) : "memory");
}
// counter poll: sum of 8 lines, single batched round trip
__device__ __forceinline__ int sum8_bar(const int* b) {
  int v0, v1, v2, v3, v4, v5, v6, v7;
  asm volatile(
      "global_load_dword %0, %8, off sc0 sc1\n\t"
      "global_load_dword %1, %9, off sc0 sc1\n\t"
      "global_load_dword %2, %10, off sc0 sc1\n\t"
      "global_load_dword %3, %11, off sc0 sc1\n\t"
      "global_load_dword %4, %12, off sc0 sc1\n\t"
      "global_load_dword %5, %13, off sc0 sc1\n\t"
      "global_load_dword %6, %14, off sc0 sc1\n\t"
      "global_load_dword %7, %15, off sc0 sc1\n\t"
      "s_waitcnt vmcnt(0)"
      : "=&v"(v0), "=&v"(v1), "=&v"(v2), "=&v"(v3),
        "=&v"(v4), "=&v"(v5), "=&v"(v6), "=&v"(v7)
      : "v"(b), "v"(b + 64), "v"(b + 128), "v"(b + 192),
        "v"(b + 256), "v"(b + 320), "v"(b + 384), "v"(b + 448)
      : "memory");
  return ((v0 + v1) + (v2 + v3)) + ((v4 + v5) + (v6 + v7));
}

// ---------------- weight re-layout: gate-interleaved Wx/Wh/bl + k-major Wp ----------------
__global__ __launch_bounds__(256) void prep_kernel(const float* __restrict__ Wx,
                                                   const float* __restrict__ Wh,
                                                   const float* __restrict__ bl,
                                                   const float* __restrict__ Wp,
                                                   float* __restrict__ ws) {
  float* WXI = ws + OFF_WXI;
  float* WHI = ws + OFF_WHI;
  float* BLI = ws + OFF_BLI;
  float* WPT = ws + OFF_WPT;
  const int t0 = 409 * 2048;
  const int t1 = t0 + 512 * 2048;
  const int t2 = t1 + 2048;
  const int total = t2 + 163840;
  for (int idx = blockIdx.x * blockDim.x + threadIdx.x; idx < total;
       idx += gridDim.x * blockDim.x) {
    if (idx < t0) {
      int k = idx >> 11, cc = idx & 2047;
      WXI[idx] = Wx[(size_t)k * 2048 + (cc & 3) * 512 + (cc >> 2)];
    } else if (idx < t1) {
      int j = idx - t0;
      int k = j >> 11, cc = j & 2047;
      WHI[j] = Wh[(size_t)k * 2048 + (cc & 3) * 512 + (cc >> 2)];
    } else if (idx < t2) {
      int cc = idx - t1;
      BLI[cc] = bl[(cc & 3) * 512 + (cc >> 2)];
    } else {
      // WPT[k4][j][ks] = Wp[k4*4+ks][j]
      int e = idx - t2;
      int k4 = e / 1280, r = e - k4 * 1280;
      int j = r >> 2, ks = r & 3;
      WPT[e] = Wp[(size_t)(k4 * 4 + ks) * 320 + j];
    }
  }
}

// ---------------- conv stack (validated) ----------------
__global__ __launch_bounds__(128) void conv_kernel(
    const float* __restrict__ img,
    const float* __restrict__ k1, const float* __restrict__ cb1, const float* __restrict__ g1,
    const float* __restrict__ be1, const float* __restrict__ mm1, const float* __restrict__ mv1,
    const float* __restrict__ k2, const float* __restrict__ cb2, const float* __restrict__ g2,
    const float* __restrict__ be2, const float* __restrict__ mm2, const float* __restrict__ mv2,
    const float* __restrict__ k3, const float* __restrict__ cb3, const float* __restrict__ g3,
    const float* __restrict__ be3, const float* __restrict__ mm3, const float* __restrict__ mv3,
    float* __restrict__ ws) {
  __shared__ float s_in[784];
  __shared__ float s_y1[13 * 13 * 8];
  __shared__ float s_y2[6 * 6 * 16];
  __shared__ float s_k1[72], s_k2[1152], s_k3[4608];
  __shared__ float s_s1[8], s_b1[8], s_s2[16], s_b2[16], s_s3[32], s_b3[32];
  float* FEATP = ws + OFF_FEATP;
  const int n = blockIdx.x, tid = threadIdx.x;
  const float* ip = img + (size_t)n * 784;
  for (int i = tid; i < 784; i += 128) s_in[i] = ip[i];
  for (int i = tid; i < 72; i += 128) s_k1[i] = k1[i];
  for (int i = tid; i < 1152; i += 128) s_k2[i] = k2[i];
  for (int i = tid; i < 4608; i += 128) s_k3[i] = k3[i];
  if (tid < 8) {
    float s = g1[tid] * rsqrtf(mv1[tid] + 1e-3f);
    s_s1[tid] = s; s_b1[tid] = (cb1[tid] - mm1[tid]) * s + be1[tid];
  } else if (tid >= 32 && tid < 48) {
    int c = tid - 32;
    float s = g2[c] * rsqrtf(mv2[c] + 1e-3f);
    s_s2[c] = s; s_b2[c] = (cb2[c] - mm2[c]) * s + be2[c];
  } else if (tid >= 64 && tid < 96) {
    int c = tid - 64;
    float s = g3[c] * rsqrtf(mv3[c] + 1e-3f);
    s_s3[c] = s; s_b3[c] = (cb3[c] - mm3[c]) * s + be3[c];
  }
  __syncthreads();
  for (int idx = tid; idx < 13 * 13 * 8; idx += 128) {
    int co = idx & 7, pos = idx >> 3;
    int j = pos % 13, i = pos / 13;
    float acc = 0.f;
    #pragma unroll
    for (int ky = 0; ky < 3; ++ky)
      #pragma unroll
      for (int kx = 0; kx < 3; ++kx)
        acc += s_in[(2 * i + ky) * 28 + (2 * j + kx)] * s_k1[(ky * 3 + kx) * 8 + co];
    float v = acc * s_s1[co] + s_b1[co];
    s_y1[idx] = v > 0.f ? v : 0.f;
  }
  __syncthreads();
  for (int idx = tid; idx < 6 * 6 * 16; idx += 128) {
    int co = idx & 15, pos = idx >> 4;
    int j = pos % 6, i = pos / 6;
    float acc = 0.f;
    for (int ky = 0; ky < 3; ++ky)
      for (int kx = 0; kx < 3; ++kx) {
        int base = ((2 * i + ky) * 13 + (2 * j + kx)) * 8;
        int kb = (ky * 3 + kx) * 128 + co;
        #pragma unroll
        for (int ci = 0; ci < 8; ++ci) acc += s_y1[base + ci] * s_k2[kb + ci * 16];
      }
    float v = acc * s_s2[co] + s_b2[co];
    s_y2[idx] = v > 0.f ? v : 0.f;
  }
  __syncthreads();
  for (int idx = tid; idx < 128; idx += 128) {
    int co = idx & 31, pos = idx >> 5;
    int j = pos & 1, i = pos >> 1;
    float acc = 0.f;
    for (int ky = 0; ky < 3; ++ky)
      for (int kx = 0; kx < 3; ++kx) {
        int base = ((2 * i + ky) * 6 + (2 * j + kx)) * 16;
        int kb = (ky * 3 + kx) * 512 + co;
        #pragma unroll
        for (int ci = 0; ci < 16; ++ci) acc += s_y2[base + ci] * s_k3[kb + ci * 32];
      }
    float v = acc * s_s3[co] + s_b3[co];
    FEATP[(size_t)n * 128 + idx] = v > 0.f ? v : 0.f;
  }
}

// ---------------- persistent LSTM scan: tagged-pair dataflow ----------------
// Roles: AZ 0-63 | AO 64-79 | ZH 80-143 (E64, K-halves) | OL 144-159 /
// OHI 160-175 | ATT 176-239 (wave-autonomous, ZERO block barriers) |
// WV 240-243 | COUT 244-251 | 252-255 idle.
// Epochs: h_t/rv_t/ZP_t/OH_t/WVP_t -> tag t+1; OUTPRE (AO step t) -> tag t.
// Zeroed buffers (tag 0) ARE the t=0 zero state.
__global__ __launch_bounds__(512) void lstm_kernel(
    const int* __restrict__ labels,
    const float* __restrict__ Wo, const float* __restrict__ bo,
    const float* __restrict__ Wp, const float* __restrict__ bp,
    const float* __restrict__ Wf, const float* __restrict__ bf,
    float* __restrict__ ws, float* __restrict__ out) {
  extern __shared__ float dyn[];
  const float* FEATP = ws + OFF_FEATP;
  const float* WXI   = ws + OFF_WXI;
  const float* WHI   = ws + OFF_WHI;
  const float* BLI   = ws + OFF_BLI;
  float* ZP2A   = ws + OFF_ZP2A;
  float* ZP2B   = ws + OFF_ZP2B;
  float* OH2A   = ws + OFF_OH2A;
  float* OH2B   = ws + OFF_OH2B;
  float* OUTPRE2= ws + OFF_OUTPRE2;
  float* HT2    = ws + OFF_HT2;     // [2][512][32]p
  float* HTT2   = ws + OFF_HTT2;    // [2][32][512]p
  float* RVT2   = ws + OFF_RVT2;    // [2][256][32]p
  float* WVP2   = ws + OFF_WVP2;    // [2][2][32][64]p
  const float* WPT = ws + OFF_WPT;  // [128][320][4]
  int*   BARp   = (int*)(ws + OFF_BAR);

  const int bid = blockIdx.x;
  const int tid = threadIdx.x;

  // cached WAR wait: skip the LLC poll when the cached read already covers it.
  int* bc = (int*)(dyn + 34808);
  auto waitC = [&](int base, int target, int& cache) {
    if (cache >= target) return;
    if (tid == 0) {
      int v = sum8_bar(BARp + base);
      while (v < target) v = sum8_bar(BARp + base);
      bc[base >> 9] = v;
    }
    __syncthreads();
    cache = bc[base >> 9];
    __syncthreads();
  };
  auto bumpC = [&](int base) {
    asm volatile("s_waitcnt vmcnt(0)" ::: "memory");
    __syncthreads();
    if (tid == 0) atomicAdd(&BARp[base + ((bid & 7) << 6)], 1);
  };

  // spin-stage an 8192-value pair buffer ([256][32]p) into [256][36]-padded LDS
  auto stageP = [&](float* dst, const float* srcPairs, int tag) {
    const iv4* sp = (const iv4*)srcPairs + tid;
    iv4 v[8];
    for (;;) {
      ld8i4_sc(sp, v);
      bool ok = true;
      #pragma unroll
      for (int j = 0; j < 8; ++j) ok = ok && (v[j][1] == tag) && (v[j][3] == tag);
      if (ok) break;
      __builtin_amdgcn_s_sleep(2);
    }
    #pragma unroll
    for (int j = 0; j < 8; ++j) {
      int i = (tid + j * 512) << 1;
      float2 f = {__int_as_float(v[j][0]), __int_as_float(v[j][2])};
      *(float2*)&dst[(i >> 5) * 36 + (i & 31)] = f;
    }
  };

  // ---- E32: Y[32c][32b] (validated). K mult of 16.
  auto E32 = [&](const float* Wm, const float* Am, int K, float* part, float2& r) {
    const int wv = tid >> 6, l = tid & 63;
    const int ksub = l & 1, cg = (l >> 1) & 3, bg = l >> 3;
    const int Kp = K >> 4;
    const int kb = wv * (K >> 3) + ksub * Kp;
    const float* wp = Wm + (size_t)kb * 32 + cg * 8;
    const float* ap = Am + (size_t)kb * 36 + bg * 4;
    float4 acc[8];
    #pragma unroll
    for (int i = 0; i < 8; ++i) acc[i] = {0.f, 0.f, 0.f, 0.f};
    #pragma unroll 4
    for (int kk = 0; kk < Kp; ++kk) {
      float4 w0 = *(const float4*)(wp + kk * 32);
      float4 w1 = *(const float4*)(wp + kk * 32 + 4);
      float4 a  = *(const float4*)(ap + kk * 36);
      float wl[8];
      *(float4*)&wl[0] = w0; *(float4*)&wl[4] = w1;
      #pragma unroll
      for (int i = 0; i < 8; ++i) {
        acc[i].x = fmaf(wl[i], a.x, acc[i].x);
        acc[i].y = fmaf(wl[i], a.y, acc[i].y);
        acc[i].z = fmaf(wl[i], a.z, acc[i].z);
        acc[i].w = fmaf(wl[i], a.w, acc[i].w);
      }
    }
    #pragma unroll
    for (int i = 0; i < 8; ++i) {
      acc[i].x += __shfl_xor(acc[i].x, 1, 64);
      acc[i].y += __shfl_xor(acc[i].y, 1, 64);
      acc[i].z += __shfl_xor(acc[i].z, 1, 64);
      acc[i].w += __shfl_xor(acc[i].w, 1, 64);
    }
    const int ob = (cg * 8) * 36 + bg * 4;
    if (ksub == 0 && wv < 4) {
      float* pb = part + wv * 1152 + ob;
      #pragma unroll
      for (int i = 0; i < 8; ++i) *(float4*)(pb + i * 36) = acc[i];
    }
    __syncthreads();
    if (ksub == 0 && wv >= 4) {
      float* pb = part + (wv - 4) * 1152 + ob;
      #pragma unroll
      for (int i = 0; i < 8; ++i) {
        float4 t = *(float4*)(pb + i * 36);
        t.x += acc[i].x; t.y += acc[i].y; t.z += acc[i].z; t.w += acc[i].w;
        *(float4*)(pb + i * 36) = t;
      }
    }
    __syncthreads();
    const int c = tid & 31, b2 = (tid >> 5) * 2;
    const int o = c * 36 + b2;
    float2 s0 = *(float2*)(part + o);
    float2 s1 = *(float2*)(part + 1152 + o);
    float2 s2 = *(float2*)(part + 2304 + o);
    float2 s3 = *(float2*)(part + 3456 + o);
    r.x = (s0.x + s1.x) + (s2.x + s3.x);
    r.y = (s0.y + s1.y) + (s2.y + s3.y);
  };

  // ---- E64: Y[64c][32b], K=256, rotated weight slab (validated).
  auto E64 = [&](const float* Wm, const float* Am, float* part, float4& r) {
    const int wv = tid >> 6, l = tid & 63;
    const int ksub = l & 1, cg = (l >> 1) & 7, bg = l >> 4;
    const int kb = wv * 32 + ksub * 16;
    const float* wp0 = Wm + (size_t)kb * 64 + ((cg * 8 + ksub * 4) & 63);
    const float* wp1 = Wm + (size_t)kb * 64 + ((cg * 8 + 4 + ksub * 4) & 63);
    const float* ap = Am + (size_t)kb * 36 + bg * 8;
    float4 acc[8][2];
    #pragma unroll
    for (int i = 0; i < 8; ++i) { acc[i][0] = {0.f,0.f,0.f,0.f}; acc[i][1] = {0.f,0.f,0.f,0.f}; }
    #pragma unroll 2
    for (int kk = 0; kk < 16; ++kk) {
      float4 w0 = *(const float4*)(wp0 + kk * 64);
      float4 w1 = *(const float4*)(wp1 + kk * 64);
      float4 a0 = *(const float4*)(ap + kk * 36);
      float4 a1 = *(const float4*)(ap + kk * 36 + 4);
      float wl[8];
      *(float4*)&wl[0] = w0; *(float4*)&wl[4] = w1;
      #pragma unroll
      for (int i = 0; i < 8; ++i) {
        acc[i][0].x = fmaf(wl[i], a0.x, acc[i][0].x);
        acc[i][0].y = fmaf(wl[i], a0.y, acc[i][0].y);
        acc[i][0].z = fmaf(wl[i], a0.z, acc[i][0].z);
        acc[i][0].w = fmaf(wl[i], a0.w, acc[i][0].w);
        acc[i][1].x = fmaf(wl[i], a1.x, acc[i][1].x);
        acc[i][1].y = fmaf(wl[i], a1.y, acc[i][1].y);
        acc[i][1].z = fmaf(wl[i], a1.z, acc[i][1].z);
        acc[i][1].w = fmaf(wl[i], a1.w, acc[i][1].w);
      }
    }
    #pragma unroll
    for (int i = 0; i < 8; ++i) {
      #pragma unroll
      for (int j = 0; j < 2; ++j) {
        acc[i][j].x += __shfl_xor(acc[i][j].x, 1, 64);
        acc[i][j].y += __shfl_xor(acc[i][j].y, 1, 64);
        acc[i][j].z += __shfl_xor(acc[i][j].z, 1, 64);
        acc[i][j].w += __shfl_xor(acc[i][j].w, 1, 64);
      }
    }
    const int ob = (cg * 8) * 36 + bg * 8;
    if (ksub == 0 && wv < 4) {
      float* pb = part + wv * 2304 + ob;
      #pragma unroll
      for (int i = 0; i < 8; ++i) {
        *(float4*)(pb + i * 36) = acc[i][0];
        *(float4*)(pb + i * 36 + 4) = acc[i][1];
      }
    }
    __syncthreads();
    if (ksub == 0 && wv >= 4) {
      float* pb = part + (wv - 4) * 2304 + ob;
      #pragma unroll
      for (int i = 0; i < 8; ++i) {
        float4 t0 = *(float4*)(pb + i * 36);
        float4 t1 = *(float4*)(pb + i * 36 + 4);
        t0.x += acc[i][0].x; t0.y += acc[i][0].y; t0.z += acc[i][0].z; t0.w += acc[i][0].w;
        t1.x += acc[i][1].x; t1.y += acc[i][1].y; t1.z += acc[i][1].z; t1.w += acc[i][1].w;
        *(float4*)(pb + i * 36) = t0;
        *(float4*)(pb + i * 36 + 4) = t1;
      }
    }
    __syncthreads();
    const int c = tid & 63, b4 = (tid >> 6) * 4;
    const int o = c * 36 + b4;
    float4 s0 = *(float4*)(part + o);
    float4 s1 = *(float4*)(part + 2304 + o);
    float4 s2 = *(float4*)(part + 4608 + o);
    float4 s3 = *(float4*)(part + 6912 + o);
    r.x = (s0.x + s1.x) + (s2.x + s3.x);
    r.y = (s0.y + s1.y) + (s2.y + s3.y);
    r.z = (s0.z + s1.z) + (s2.z + s3.z);
    r.w = (s0.w + s1.w) + (s2.w + s3.w);
  };

  // ---------------- one-time init: weights -> LDS ----------------
  if (bid < 64) {            // AZ: Wz (rv part of Wx) + Wxx (x part)
    const int c0 = bid * 32;
    for (int i = tid; i < 8192; i += 512)
      dyn[i] = WXI[(size_t)(153 + (i >> 5)) * 2048 + c0 + (i & 31)];
    for (int i = tid; i < 4096; i += 512)
      dyn[8192 + i] = WXI[(size_t)(i >> 5) * 2048 + c0 + (i & 31)];
    if (tid < 256) dyn[12288 + tid] = 0.f;  // Cst
  } else if (bid < 80) {     // AO: Wo rows 512..768
    const int u0 = (bid - 64) * 32;
    for (int i = tid; i < 8192; i += 512)
      dyn[i] = Wo[(size_t)(512 + (i >> 5)) * 512 + u0 + (i & 31)];
    if (tid < 32) dyn[8192 + tid] = bo[u0 + tid];
  } else if (bid < 144) {    // ZH: rotated E64 slab Wh[kh*256..+256][j0..j0+64]
    const int r = bid - 80;
    const int j0 = (r & 31) * 64, kh = r >> 5;
    for (int i = tid; i < 16384; i += 512) {
      int k = i >> 6, cc = i & 63;
      int cr = (cc + ((k >> 4) & 1) * 4) & 63;
      dyn[k * 64 + cr] = WHI[(size_t)(kh * 256 + k) * 2048 + j0 + cc];
    }
  } else if (bid < 160) {    // OL: Wo rows 0..256
    const int u0 = (bid - 144) * 32;
    for (int i = tid; i < 8192; i += 512)
      dyn[i] = Wo[(size_t)(i >> 5) * 512 + u0 + (i & 31)];
  } else if (bid < 176) {    // OHI: Wo rows 256..512
    const int u0 = (bid - 160) * 32;
    for (int i = tid; i < 8192; i += 512)
      dyn[i] = Wo[(size_t)(256 + (i >> 5)) * 512 + u0 + (i & 31)];
  } else if (bid < 240) {    // ATT: ring + cached norms + bias slices + flags
    const int hp = (bid - 176) & 1;
    for (int i = tid; i < 17000; i += 512) dyn[i] = 0.f;            // ring[250][68]
    if (tid < 256) dyn[17000 + tid] = rsqrtf(1e-12f);               // rn
    if (tid < 128) dyn[21264 + tid] = bp[64 + hp * 128 + tid];      // bpk
    if (tid < 64)  dyn[21392 + tid] = bp[tid];                      // bpw
    if (tid < 4)   ((int*)(dyn + 21456))[tid] = 0;                  // flags
  } else if (bid < 244) {    // WV: Wp[kh*256..+256][cp*32..+32]
    const int kh = (bid - 240) >> 1, cp = (bid - 240) & 1;
    for (int i = tid; i < 8192; i += 512) {
      int k = i >> 5, c = i & 31;
      dyn[i] = Wp[(size_t)(kh * 256 + k) * 320 + cp * 32 + c];
    }
  } else if (bid < 252) {    // COUT: Wf + bf
    for (int i = tid; i < 12800; i += 512) dyn[i] = Wf[i];
    if (tid < 25) dyn[12800 + tid] = bf[tid];
  }
  __syncthreads();

  // ================= role bodies =================
  // AZ dyn: Wz[0,8192) Wxx[8192,12288) Cst[12288,12544) rvT[12544,21760)
  //         xT[21760,26368) zx[26368,27392) zf[27392,28416) part[28416,33024)
  auto azStage = [&](int t) {
    const float* rvP = RVT2 + ((t + 1) & 1) * 16384;
    const float* zaP = ZP2A + (t & 1) * 131072;
    const float* zbP = ZP2B + (t & 1) * 131072;
    float* rvT = dyn + 12544; float* zf = dyn + 27392;
    const int bb = tid >> 4, c2 = tid & 15;
    const iv4* rp = (const iv4*)rvP + tid;
    const size_t zi = (size_t)bb * 1024 + bid * 16 + c2;
    const iv4* za = (const iv4*)zaP + zi;
    const iv4* zb = (const iv4*)zbP + zi;
    iv4 v[10];
    for (;;) {
      ld10i4_sc(rp, za, zb, v);
      bool ok = true;
      #pragma unroll
      for (int j = 0; j < 8; ++j) ok = ok && (v[j][1] == t) && (v[j][3] == t);
      ok = ok && (v[8][1] == t + 1) && (v[8][3] == t + 1) &&
                 (v[9][1] == t + 1) && (v[9][3] == t + 1);
      if (ok) break;
      __builtin_amdgcn_s_sleep(1);
    }
    #pragma unroll
    for (int j = 0; j < 8; ++j) {
      int i = (tid + j * 512) << 1;
      float2 f = {__int_as_float(v[j][0]), __int_as_float(v[j][2])};
      *(float2*)&rvT[(i >> 5) * 36 + (i & 31)] = f;
    }
    float2 s = {__int_as_float(v[8][0]) + __int_as_float(v[9][0]),
                __int_as_float(v[8][2]) + __int_as_float(v[9][2])};
    *(float2*)&zf[bb * 32 + c2 * 2] = s;
  };
  auto azX = [&](int tt) {    // zx = x_{tt}@Wx, local
    float* Wxx = dyn + 8192; float* xT = dyn + 21760;
    float* zx = dyn + 26368; float* part = dyn + 28416;
    for (int i = tid; i < 4096; i += 512) {
      int b = i >> 7, k = i & 127;
      xT[k * 36 + b] = FEATP[((size_t)b * 250 + tt) * 128 + k];
    }
    __syncthreads();
    float2 r;
    E32(Wxx, xT, 128, part, r);
    const int c = tid & 31, b2 = (tid >> 5) * 2;
    zx[b2 * 32 + c] = r.x;
    zx[(b2 + 1) * 32 + c] = r.y;
  };
  // AO dyn: W[0,8192) bo[8192,8224) rvT[8224,17440) of[17440,18464) part[18464,23072)
  auto aoOut = [&](int t) {   // outpre_{t-1}: rv_{t-1} (tag t), OH_{t-1} (tag t)
    const int u0 = (bid - 64) * 32;
    const float* rvP  = RVT2 + ((t + 1) & 1) * 16384;
    const float* ohaP = OH2A + ((t + 1) & 1) * 32768;
    const float* ohbP = OH2B + ((t + 1) & 1) * 32768;
    float* W = dyn; float* bo_l = dyn + 8192; float* rvT = dyn + 8224;
    float* of = dyn + 17440; float* part = dyn + 18464;
    {
      const int b = tid >> 4, c2 = tid & 15;
      const iv4* rp = (const iv4*)rvP + tid;
      const iv4* za = (const iv4*)ohaP + (b * 256 + (u0 >> 1) + c2);
      const iv4* zb = (const iv4*)ohbP + (b * 256 + (u0 >> 1) + c2);
      iv4 v[10];
      for (;;) {
        ld10i4_sc(rp, za, zb, v);
        bool ok = true;
        #pragma unroll
        for (int j = 0; j < 10; ++j) ok = ok && (v[j][1] == t) && (v[j][3] == t);
        if (ok) break;
        __builtin_amdgcn_s_sleep(2);
      }
      #pragma unroll
      for (int j = 0; j < 8; ++j) {
        int i = (tid + j * 512) << 1;
        float2 f = {__int_as_float(v[j][0]), __int_as_float(v[j][2])};
        *(float2*)&rvT[(i >> 5) * 36 + (i & 31)] = f;
      }
      float2 s = {__int_as_float(v[8][0]) + __int_as_float(v[9][0]),
                  __int_as_float(v[8][2]) + __int_as_float(v[9][2])};
      *(float2*)&of[b * 32 + c2 * 2] = s;
    }
    __syncthreads();
    float2 r;
    E32(W, rvT, 256, part, r);
    const int c = tid & 31, b2 = (tid >> 5) * 2;
    float bv = bo_l[c];
    st_pair(OUTPRE2, (size_t)b2 * 512 + u0 + c, r.x + of[b2 * 32 + c] + bv, t);
    st_pair(OUTPRE2, (size_t)(b2 + 1) * 512 + u0 + c, r.y + of[(b2 + 1) * 32 + c] + bv, t);
  };
  // OL/OHI dyn: W[0,8192) A[8192,17408) part[17408,22016)
  auto p2Gemm = [&](int t) {
    const float* htP = HT2 + (t & 1) * 32768;
    float* W = dyn; float* A = dyn + 8192; float* part = dyn + 17408;
    const bool isOLr = bid < 160;
    stageP(A, isOLr ? htP : (htP + 16384), t + 1);
    __syncthreads();
    float2 r;
    E32(W, A, 256, part, r);
    const int c = tid & 31, b2 = (tid >> 5) * 2;
    const int u0 = (isOLr ? (bid - 144) : (bid - 160)) * 32;
    float* d = (isOLr ? OH2A : OH2B) + (t & 1) * 32768;
    st_pair(d, (size_t)b2 * 512 + u0 + c, r.x, t + 1);
    st_pair(d, (size_t)(b2 + 1) * 512 + u0 + c, r.y, t + 1);
  };

  // ---------------- dataflow role loops ----------------
  if (bid < 64) {                       // AZ
    int cCOH = 0;
    float* Wz = dyn; float* Cst = dyn + 12288; float* rvT = dyn + 12544;
    float* zx = dyn + 26368; float* zf = dyn + 27392; float* part = dyn + 28416;
    azX(0);
    for (int t = 0; t < 250; ++t) {
      azStage(t);                                // RAW ZP_t + rv_{t-1}, one RTT
      if (t >= 2) waitC(COH, 32 * (t - 1), cCOH);// HT WAR: OL/OHI_{t-2} read done
      __syncthreads();
      float2 r;
      E32(Wz, rvT, 256, part, r);
      const int c = tid & 31, b2 = (tid >> 5) * 2;
      zf[b2 * 32 + c] += r.x + zx[b2 * 32 + c];
      zf[(b2 + 1) * 32 + c] += r.y + zx[(b2 + 1) * 32 + c];
      __syncthreads();
      if (tid < 256) {
        int u = tid & 7, b = tid >> 3;
        float4 z = *(float4*)(zf + b * 32 + u * 4);
        float ig = sigm(z.x), fg = sigm(z.y), gg = tanhf(z.z), og = sigm(z.w);
        float cc = fg * Cst[b * 8 + u] + ig * gg;
        Cst[b * 8 + u] = cc;
        float hv = og * tanhf(cc);
        st_pair(HT2 + (t & 1) * 32768, (size_t)(bid * 8 + u) * 32 + b, hv, t + 1);
        st_pair(HTT2 + (t & 1) * 32768, (size_t)b * 512 + bid * 8 + u, hv, t + 1);
      }
      if (t < 249) azX(t + 1);
    }
  } else if (bid < 80) {                // AO
    int cCCO = 0;
    for (int t = 1; t <= 250; ++t) {
      if (t >= 2) waitC(CCO, 8 * (t - 1), cCCO); // OUTPRE WAR: COUT_{t-1} done
      aoOut(t);                                  // RAW rv/OH via tags
      bumpC(COP);
    }
  } else if (bid < 144) {               // ZH: E64 k-half partial of h@Wh
    const int r = bid - 80;
    const int j0 = (r & 31) * 64, kh = r >> 5;
    const int c = tid & 63, b4 = (tid >> 6) * 4;
    float* W = dyn; float* A = dyn + 16384; float* part = dyn + 25600;
    float* zpBase = kh ? ZP2B : ZP2A;
    const float blv = (kh == 0) ? BLI[j0 + c] : 0.f;
    for (int s = 0; s < 250; ++s) {
      float wx0 = 0.f, wx1 = 0.f, wx2 = 0.f, wx3 = 0.f;
      if (kh == 0) {     // label-row prefetch (input-dependent only)
        int l0 = labels[(b4 + 0) * 250 + s], l1 = labels[(b4 + 1) * 250 + s];
        int l2 = labels[(b4 + 2) * 250 + s], l3 = labels[(b4 + 3) * 250 + s];
        wx0 = WXI[(size_t)(128 + l0) * 2048 + j0 + c];
        wx1 = WXI[(size_t)(128 + l1) * 2048 + j0 + c];
        wx2 = WXI[(size_t)(128 + l2) * 2048 + j0 + c];
        wx3 = WXI[(size_t)(128 + l3) * 2048 + j0 + c];
      }
      stageP(A, HT2 + ((s + 1) & 1) * 32768 + kh * 16384, s);  // h_{s-1} half
      __syncthreads();
      float4 rr;
      E64(W, A, part, rr);
      float* zpD = zpBase + (s & 1) * 131072;
      st_pair(zpD, (size_t)(b4 + 0) * 2048 + j0 + c, rr.x + blv + wx0, s + 1);
      st_pair(zpD, (size_t)(b4 + 1) * 2048 + j0 + c, rr.y + blv + wx1, s + 1);
      st_pair(zpD, (size_t)(b4 + 2) * 2048 + j0 + c, rr.z + blv + wx2, s + 1);
      st_pair(zpD, (size_t)(b4 + 3) * 2048 + j0 + c, rr.w + blv + wx3, s + 1);
    }
  } else if (bid < 176) {               // OL / OHI
    int cCOP = 0;
    for (int t = 0; t < 250; ++t) {
      if (t >= 2) waitC(COP, 16 * (t - 1), cCOP);// OH WAR: AO_{t-1} read done
      p2Gemm(t);                                 // RAW h_t via tags
      bumpC(COH);
    }
  } else if (bid < 240) {               // ATT: wave-autonomous, ZERO barriers
    // LDS: ring[0,17000) rn[17000,17256) hS[17256+w*512) knS[18280+w*64)
    //      attS[18408+w*256) bpk[21264) bpw[21392) flags@21456 (ints)
    float* ring = dyn;
    float* rn   = dyn + 17000;
    int* flags  = (int*)(dyn + 21456);  // [2] = ring version (updates applied)
    const int b = (bid - 176) >> 1, hp = (bid - 176) & 1;
    const int w = tid >> 6, l = tid & 63;

    if (w < 2) {            // head wave: global head g = 2*hp + w
      float* hS   = dyn + 17256 + w * 512;
      float* knS  = dyn + 18280 + w * 64;
      float* attS = dyn + 18408 + w * 256;
      const float bpkv = dyn[21264 + w * 64 + l];
      const fv4* wb = (const fv4*)WPT + (64 + hp * 128 + w * 64 + l);
      const int m16 = l & 15, dg = l >> 4;
      int copC = 0;
      for (int t = 0; t < 250; ++t) {
        { // per-lane h spin: dims l*8..l*8+8 of h_t (tag t+1)
          const iv4* hb = (const iv4*)(HTT2 + (t & 1) * 32768) + b * 256 + l * 4;
          iv4 a0, a1, a2, a3;
          for (;;) {
            ld4i4o_sc(hb, a0, a1, a2, a3);
            if (a0[1] == t + 1 && a0[3] == t + 1 && a1[1] == t + 1 && a1[3] == t + 1 &&
                a2[1] == t + 1 && a2[3] == t + 1 && a3[1] == t + 1 && a3[3] == t + 1)
              break;
            __builtin_amdgcn_s_sleep(1);
          }
          float2 f;
          f = {__int_as_float(a0[0]), __int_as_float(a0[2])}; *(float2*)&hS[l * 8 + 0] = f;
          f = {__int_as_float(a1[0]), __int_as_float(a1[2])}; *(float2*)&hS[l * 8 + 2] = f;
          f = {__int_as_float(a2[0]), __int_as_float(a2[2])}; *(float2*)&hS[l * 8 + 4] = f;
          f = {__int_as_float(a3[0]), __int_as_float(a3[2])}; *(float2*)&hS[l * 8 + 6] = f;
        }
        asm volatile("s_waitcnt lgkmcnt(0)" ::: "memory");
        __builtin_amdgcn_sched_barrier(0);
        // key GEMM (streamed Wp): kn[l] = tanh(sum_k h[k]*Wp[k][J])
        float acc = 0.f;
        #pragma unroll 8
        for (int k4 = 0; k4 < 128; ++k4) {
          fv4 wv4 = wb[(size_t)k4 * 320];
          fv4 h4 = *(const fv4*)&hS[k4 * 4];
          acc = fmaf(wv4.x, h4.x, acc);
          acc = fmaf(wv4.y, h4.y, acc);
          acc = fmaf(wv4.z, h4.z, acc);
          acc = fmaf(wv4.w, h4.w, acc);
        }
        float kv = tanhf(acc + bpkv);
        float pq = kv * kv;
        #pragma unroll
        for (int off = 32; off; off >>= 1) pq += __shfl_xor(pq, off, 64);
        knS[l] = kv * rsqrtf(fmaxf(pq, 1e-12f));
        asm volatile("s_waitcnt lgkmcnt(0)" ::: "memory");
        __builtin_amdgcn_sched_barrier(0);
        // ring version gate: updates through t-1 applied (RAW on ring/rn)
        if (t >= 1) {
          while (__hip_atomic_load(&flags[2], __ATOMIC_ACQUIRE,
                                   __HIP_MEMORY_SCOPE_WORKGROUP) < t) {}
          __builtin_amdgcn_sched_barrier(0);
        }
        const fv4 kq0 = *(const fv4*)&knS[dg * 16 + 0];
        const fv4 kq1 = *(const fv4*)&knS[dg * 16 + 4];
        const fv4 kq2 = *(const fv4*)&knS[dg * 16 + 8];
        const fv4 kq3 = *(const fv4*)&knS[dg * 16 + 12];
        const int start = 250 - t;       // live cells m<t at rows start+m (no wrap)
        // dots + exp: dead cells (m>=t) are zero vectors -> e = 1 exactly.
        float lsum = 0.f;
        const int jmax = (t + 15) >> 4;
        for (int j = 0; j < jmax; ++j) {
          int m = m16 + (j << 4);
          bool act = m < t;              // uniform across shfl partners (same m)
          float d = 0.f;
          if (act) {
            const fv4* c4 = (const fv4*)(ring + (start + m) * 68) + dg * 4;
            fv4 q0 = c4[0], q1 = c4[1], q2 = c4[2], q3 = c4[3];
            d = fmaf(q0.x, kq0.x, fmaf(q0.y, kq0.y, fmaf(q0.z, kq0.z, q0.w * kq0.w)));
            d = fmaf(q1.x, kq1.x, fmaf(q1.y, kq1.y, fmaf(q1.z, kq1.z, fmaf(q1.w, kq1.w, d))));
            d = fmaf(q2.x, kq2.x, fmaf(q2.y, kq2.y, fmaf(q2.z, kq2.z, fmaf(q2.w, kq2.w, d))));
            d = fmaf(q3.x, kq3.x, fmaf(q3.y, kq3.y, fmaf(q3.z, kq3.z, fmaf(q3.w, kq3.w, d))));
          }
          d += __shfl_xor(d, 16, 64);
          d += __shfl_xor(d, 32, 64);
          if (act) {
            float e = __expf(d * rn[start + m]);
            if (dg == 0) attS[m] = e;
            lsum += e;
          }
        }
        #pragma unroll
        for (int off = 8; off; off >>= 1) lsum += __shfl_xor(lsum, off, 64);
        float denom = lsum + (float)(250 - t);
        asm volatile("s_waitcnt lgkmcnt(0)" ::: "memory");
        __builtin_amdgcn_sched_barrier(0);
        // wsum over live cells (lane l = cell dim)
        const float* rb = ring + start * 68 + l;
        float racc = 0.f;
        int m = 0;
        for (; m + 4 <= t; m += 4) {
          fv4 a4 = *(const fv4*)&attS[m];
          racc = fmaf(a4.x, rb[(m + 0) * 68], racc);
          racc = fmaf(a4.y, rb[(m + 1) * 68], racc);
          racc = fmaf(a4.z, rb[(m + 2) * 68], racc);
          racc = fmaf(a4.w, rb[(m + 3) * 68], racc);
        }
        for (; m < t; ++m) racc = fmaf(attS[m], rb[m * 68], racc);
        // rv WAR: AO_{t-1} consumed rv_{t-2} slot
        if (t >= 2 && copC < 16 * (t - 1)) {
          do { copC = sum8_bar(BARp + COP); } while (copC < 16 * (t - 1));
        }
        st_pair(RVT2 + (t & 1) * 16384,
                (size_t)((2 * hp + w) * 64 + l) * 32 + b, racc / denom, t + 1);
      }
    } else if (w == 2) {     // ring-update wave (row 249-t is disjoint from
                             // step-t reads [250-t,249] -> only RAW gate needed)
      float* bpw = dyn + 21392;
      for (int t = 0; t < 250; ++t) {
        float2 p01 = spin_pair_2addr(
            WVP2 + (t & 1) * 8192 + 2 * ((size_t)b * 64 + l),
            WVP2 + (t & 1) * 8192 + 4096 + 2 * ((size_t)b * 64 + l), t + 1);
        float nv = tanhf(p01.x + p01.y + bpw[l]);
        float n2 = nv * nv;
        #pragma unroll
        for (int off = 32; off; off >>= 1) n2 += __shfl_xor(n2, off, 64);
        const int ip = 249 - t;
        ring[ip * 68 + l] = nv;
        if (l == 0) rn[ip] = rsqrtf(fmaxf(n2, 1e-12f));
        asm volatile("s_waitcnt lgkmcnt(0)" ::: "memory");
        __builtin_amdgcn_sched_barrier(0);
        if (l == 0) {
          __hip_atomic_store(&flags[2], t + 1, __ATOMIC_RELEASE,
                             __HIP_MEMORY_SCOPE_WORKGROUP);
          atomicAdd(&BARp[CRING + ((bid & 7) << 6)], 1);  // WVP_t consumed
        }
      }
    }
    // waves 3-7: exit (no __syncthreads anywhere in the ATT role loops)
  } else if (bid < 244) {               // WV: wv partials
    // dyn: W[0,8192) A[8192,17408) part[17408,22016)
    const int kh = (bid - 240) >> 1, cp = (bid - 240) & 1;
    float* W = dyn; float* A = dyn + 8192; float* part = dyn + 17408;
    int cCR = 0;
    for (int t = 0; t < 250; ++t) {
      if (t >= 2) waitC(CRING, 64 * (t - 1), cCR);// WVP WAR: ring-update done
      stageP(A, HT2 + (t & 1) * 32768 + kh * 16384, t + 1);  // RAW h_t via tags
      __syncthreads();
      float2 r;
      E32(W, A, 256, part, r);
      const int c = tid & 31, b2 = (tid >> 5) * 2;
      float* d = WVP2 + (t & 1) * 8192 + kh * 4096;
      st_pair(d, (size_t)b2 * 64 + cp * 32 + c, r.x, t + 1);
      st_pair(d, (size_t)(b2 + 1) * 64 + cp * 32 + c, r.y, t + 1);
    }
  } else if (bid < 252) {               // COUT: 4 batches, one quad spin per step
    const int b0 = (bid - 244) * 4;
    float* WfL = dyn; float* bfL = dyn + 12800;
    float* to4 = dyn + 12832;           // [4][512]
    float* lp  = dyn + 14880;           // [400]
    float* lg  = dyn + 15280;           // [27]
    for (int t = 1; t <= 250; ++t) {
      {
        const iv2* p0 = (const iv2*)(OUTPRE2 + 2 * ((size_t)(b0 + 0) * 512 + tid));
        const iv2* p1 = (const iv2*)(OUTPRE2 + 2 * ((size_t)(b0 + 1) * 512 + tid));
        const iv2* p2 = (const iv2*)(OUTPRE2 + 2 * ((size_t)(b0 + 2) * 512 + tid));
        const iv2* p3 = (const iv2*)(OUTPRE2 + 2 * ((size_t)(b0 + 3) * 512 + tid));
        iv2 v0, v1, v2, v3;
        for (;;) {
          ld4x2_sc(p0, p1, p2, p3, v0, v1, v2, v3);
          if (v0[1] == t && v1[1] == t && v2[1] == t && v3[1] == t) break;
          __builtin_amdgcn_s_sleep(2);
        }
        to4[tid]        = tanhf(__int_as_float(v0[0]));
        to4[512 + tid]  = tanhf(__int_as_float(v1[0]));
        to4[1024 + tid] = tanhf(__int_as_float(v2[0]));
        to4[1536 + tid] = tanhf(__int_as_float(v3[0]));
      }
      __syncthreads();
      for (int i = 0; i < 4; ++i) {
        float* to = to4 + i * 512;
        if (tid < 400) {
          int l = tid % 25, p = tid / 25;
          float s = 0.f;
          #pragma unroll
          for (int q = 0; q < 32; ++q) { int k = p * 32 + q; s += to[k] * WfL[k * 25 + l]; }
          lp[p * 25 + l] = s;
        }
        __syncthreads();
        if (tid < 25) {
          float s = bfL[tid];
          #pragma unroll
          for (int p = 0; p < 16; ++p) s += lp[p * 25 + tid];
          lg[tid] = s;
        }
        __syncthreads();
        if (tid == 0) {
          float mx = lg[0];
          for (int l = 1; l < 25; ++l) mx = fmaxf(mx, lg[l]);
          float ss = 0.f;
          for (int l = 0; l < 25; ++l) ss += __expf(lg[l] - mx);
          lg[25] = mx; lg[26] = 1.f / ss;
        }
        __syncthreads();
        if (tid < 25)
          out[((size_t)(b0 + i) * 250 + (t - 1)) * 25 + tid] =
              __expf(lg[tid] - lg[25]) * lg[26];
        __syncthreads();
      }
      bumpC(CCO);
    }
  }
}

extern "C" void kernel_launch(void* const* d_in, const int* in_sizes, int n_in,
                              void* d_out, int out_size, void* d_ws, size_t ws_size,
                              hipStream_t stream) {
  const float* images = (const float*)d_in[0];
  const int* labels = (const int*)d_in[1];
  const float* k1  = (const float*)d_in[2];
  const float* cb1 = (const float*)d_in[3];
  const float* g1  = (const float*)d_in[4];
  const float* be1 = (const float*)d_in[5];
  const float* mm1 = (const float*)d_in[6];
  const float* mv1 = (const float*)d_in[7];
  const float* k2  = (const float*)d_in[8];
  const float* cb2 = (const float*)d_in[9];
  const float* g2  = (const float*)d_in[10];
  const float* be2 = (const float*)d_in[11];
  const float* mm2 = (const float*)d_in[12];
  const float* mv2 = (const float*)d_in[13];
  const float* k3  = (const float*)d_in[14];
  const float* cb3 = (const float*)d_in[15];
  const float* g3  = (const float*)d_in[16];
  const float* be3 = (const float*)d_in[17];
  const float* mm3 = (const float*)d_in[18];
  const float* mv3 = (const float*)d_in[19];
  const float* Wx  = (const float*)d_in[20];
  const float* Wh  = (const float*)d_in[21];
  const float* bl  = (const float*)d_in[22];
  const float* Wp  = (const float*)d_in[23];
  const float* bp  = (const float*)d_in[24];
  const float* Wo  = (const float*)d_in[25];
  const float* bo  = (const float*)d_in[26];
  const float* Wf  = (const float*)d_in[27];
  const float* bf  = (const float*)d_in[28];
  float* ws = (float*)d_ws;

  hipFuncSetAttribute((const void*)lstm_kernel,
                      hipFuncAttributeMaxDynamicSharedMemorySize, DYN_BYTES);

  // zero all pair buffers + counters (tags -> 0 = step-0 zero state)
  hipMemsetAsync((char*)d_ws + OFF_ZP2A * sizeof(float), 0,
                 (OFF_WPT - OFF_ZP2A) * sizeof(float), stream);
  prep_kernel<<<1024, 256, 0, stream>>>(Wx, Wh, bl, Wp, ws);
  conv_kernel<<<8000, 128, 0, stream>>>(images,
      k1, cb1, g1, be1, mm1, mv1,
      k2, cb2, g2, be2, mm2, mv2,
      k3, cb3, g3, be3, mm3, mv3, ws);
  lstm_kernel<<<256, 512, DYN_BYTES, stream>>>(labels, Wo, bo, Wp, bp, Wf, bf, ws,
                                               (float*)d_out);
}

// Round 9
// 3768.175 us; speedup vs baseline: 1.2848x; 1.2848x over previous
//
#include <hip/hip_runtime.h>

// ---------------- problem constants ----------------
// B=32, T=250, FEAT=128, CLASSES=25, UNITS=512, CELL=64, HEADS=4, IN_LSTM=409

// ---------------- scratch layout (floats) ----------------
// All inter-block activations are (value,epoch) PAIRS (8 B, stored atomically).
// rv is replicated: RVT2 (AZ readers) / RVT2B (AO readers) -> separate LLC lines.
constexpr size_t OFF_FEATP  = 0;                              // [8000][128]
constexpr size_t OFF_WXI    = OFF_FEATP + (size_t)8000 * 128; // [409][2048] gate-interleaved
constexpr size_t OFF_WHI    = OFF_WXI + (size_t)409 * 2048;   // [512][2048]
constexpr size_t OFF_BLI    = OFF_WHI + (size_t)512 * 2048;   // [2048]
constexpr size_t OFF_ZP2A   = OFF_BLI + 2048;                 // [2][32][2048]p (k-half 0 + bias/label)
constexpr size_t OFF_ZP2B   = OFF_ZP2A + 262144;              // [2][32][2048]p (k-half 1)
constexpr size_t OFF_OH2A   = OFF_ZP2B + 262144;              // [2][32][512]p
constexpr size_t OFF_OH2B   = OFF_OH2A + 65536;               // [2][32][512]p
constexpr size_t OFF_OUTPRE2= OFF_OH2B + 65536;               // [32][512]p
constexpr size_t OFF_HT2    = OFF_OUTPRE2 + 32768;            // [2][512][32]p
constexpr size_t OFF_HTT2   = OFF_HT2 + 65536;                // [2][32][512]p
constexpr size_t OFF_RVT2   = OFF_HTT2 + 65536;               // [2][256][32]p (AZ)
constexpr size_t OFF_RVT2B  = OFF_RVT2 + 32768;               // replica (AO)
constexpr size_t OFF_WVP2   = OFF_RVT2B + 32768;              // [2][2][32][64]p
constexpr size_t OFF_BAR    = OFF_WVP2 + 16384;               // counters (4096 ints)
constexpr size_t OFF_WPT    = OFF_BAR + 4096;                 // [128][320][4] k-major Wp
constexpr size_t WS_FLOATS  = OFF_WPT + (size_t)163840;

constexpr int DYN_FLOATS = 34816;                 // 136 KB dynamic LDS
constexpr int DYN_BYTES  = DYN_FLOATS * 4;

// WAR-slack counters only (8 lines x 64-int stride each). RAW sync is via tags.
constexpr int COH = 0, COP = 512, CCO = 1024, CRING = 1536;

__device__ __forceinline__ float sigm(float x) { return 1.f / (1.f + __expf(-x)); }

typedef int iv2 __attribute__((ext_vector_type(2)));
typedef int iv4 __attribute__((ext_vector_type(4)));
typedef float fv4 __attribute__((ext_vector_type(4)));

// ---- LLC-coherent accesses (bypass L1+L2). Batched loads with the waitcnt
// inside the asm so they are one round trip.
__device__ __forceinline__ void st_pair(float* base, size_t pidx, float v, int tag) {
  unsigned long long u = (unsigned long long)__float_as_uint(v) |
                         ((unsigned long long)(unsigned)tag << 32);
  __hip_atomic_store((unsigned long long*)(base + 2 * pidx), u,
                     __ATOMIC_RELAXED, __HIP_MEMORY_SCOPE_AGENT);
}
__device__ __forceinline__ float spin_pair(const float* base, size_t pidx, int tag) {
  const iv2* p = (const iv2*)(base + 2 * pidx);
  iv2 v;
  for (;;) {
    asm volatile("global_load_dwordx2 %0, %1, off sc0 sc1\n\ts_waitcnt vmcnt(0)"
                 : "=&v"(v) : "v"(p) : "memory");
    if (v[1] == tag) break;
    __builtin_amdgcn_s_sleep(1);
  }
  return __int_as_float(v[0]);
}
// two pairs at separate addresses
__device__ __forceinline__ float2 spin_pair_2addr(const float* a, const float* b, int tag) {
  const iv2* pa = (const iv2*)a;
  const iv2* pb = (const iv2*)b;
  iv2 x, y;
  for (;;) {
    asm volatile(
        "global_load_dwordx2 %0, %2, off sc0 sc1\n\t"
        "global_load_dwordx2 %1, %3, off sc0 sc1\n\t"
        "s_waitcnt vmcnt(0)"
        : "=&v"(x), "=&v"(y) : "v"(pa), "v"(pb) : "memory");
    if (x[1] == tag && y[1] == tag) break;
    __builtin_amdgcn_s_sleep(1);
  }
  return {__int_as_float(x[0]), __int_as_float(y[0])};
}
// four pairs at separate addresses (COUT quad spin)
__device__ __forceinline__ void ld4x2_sc(const iv2* a, const iv2* b, const iv2* c,
                                         const iv2* d, iv2& x, iv2& y, iv2& z, iv2& w) {
  asm volatile(
      "global_load_dwordx2 %0, %4, off sc0 sc1\n\t"
      "global_load_dwordx2 %1, %5, off sc0 sc1\n\t"
      "global_load_dwordx2 %2, %6, off sc0 sc1\n\t"
      "global_load_dwordx2 %3, %7, off sc0 sc1\n\t"
      "s_waitcnt vmcnt(0)"
      : "=&v"(x), "=&v"(y), "=&v"(z), "=&v"(w)
      : "v"(a), "v"(b), "v"(c), "v"(d) : "memory");
}
__device__ __forceinline__ void ld8i4_sc(const iv4* b0, iv4* v) {
  const iv4 *p0 = b0, *p1 = b0 + 512, *p2 = b0 + 1024, *p3 = b0 + 1536,
            *p4 = b0 + 2048, *p5 = b0 + 2560, *p6 = b0 + 3072, *p7 = b0 + 3584;
  asm volatile(
      "global_load_dwordx4 %0, %8, off sc0 sc1\n\t"
      "global_load_dwordx4 %1, %9, off sc0 sc1\n\t"
      "global_load_dwordx4 %2, %10, off sc0 sc1\n\t"
      "global_load_dwordx4 %3, %11, off sc0 sc1\n\t"
      "global_load_dwordx4 %4, %12, off sc0 sc1\n\t"
      "global_load_dwordx4 %5, %13, off sc0 sc1\n\t"
      "global_load_dwordx4 %6, %14, off sc0 sc1\n\t"
      "global_load_dwordx4 %7, %15, off sc0 sc1\n\t"
      "s_waitcnt vmcnt(0)"
      : "=&v"(v[0]), "=&v"(v[1]), "=&v"(v[2]), "=&v"(v[3]),
        "=&v"(v[4]), "=&v"(v[5]), "=&v"(v[6]), "=&v"(v[7])
      : "v"(p0), "v"(p1), "v"(p2), "v"(p3), "v"(p4), "v"(p5), "v"(p6), "v"(p7)
      : "memory");
}
// 8 strided dwordx4 (rv) + 2 dwordx4 at free addresses, one waitcnt
__device__ __forceinline__ void ld10i4_sc(const iv4* b0, const iv4* z0,
                                          const iv4* z1, iv4* v) {
  const iv4 *p0 = b0, *p1 = b0 + 512, *p2 = b0 + 1024, *p3 = b0 + 1536,
            *p4 = b0 + 2048, *p5 = b0 + 2560, *p6 = b0 + 3072, *p7 = b0 + 3584;
  asm volatile(
      "global_load_dwordx4 %0, %10, off sc0 sc1\n\t"
      "global_load_dwordx4 %1, %11, off sc0 sc1\n\t"
      "global_load_dwordx4 %2, %12, off sc0 sc1\n\t"
      "global_load_dwordx4 %3, %13, off sc0 sc1\n\t"
      "global_load_dwordx4 %4, %14, off sc0 sc1\n\t"
      "global_load_dwordx4 %5, %15, off sc0 sc1\n\t"
      "global_load_dwordx4 %6, %16, off sc0 sc1\n\t"
      "global_load_dwordx4 %7, %17, off sc0 sc1\n\t"
      "global_load_dwordx4 %8, %18, off sc0 sc1\n\t"
      "global_load_dwordx4 %9, %19, off sc0 sc1\n\t"
      "s_waitcnt vmcnt(0)"
      : "=&v"(v[0]), "=&v"(v[1]), "=&v"(v[2]), "=&v"(v[3]), "=&v"(v[4]),
        "=&v"(v[5]), "=&v"(v[6]), "=&v"(v[7]), "=&v"(v[8]), "=&v"(v[9])
      : "v"(p0), "v"(p1), "v"(p2), "v"(p3), "v"(p4), "v"(p5), "v"(p6), "v"(p7),
        "v"(z0), "v"(z1)
      : "memory");
}
// counter poll: sum of 8 lines, single batched round trip
__device__ __forceinline__ int sum8_bar(const int* b) {
  int v0, v1, v2, v3, v4, v5, v6, v7;
  asm volatile(
      "global_load_dword %0, %8, off sc0 sc1\n\t"
      "global_load_dword %1, %9, off sc0 sc1\n\t"
      "global_load_dword %2, %10, off sc0 sc1\n\t"
      "global_load_dword %3, %11, off sc0 sc1\n\t"
      "global_load_dword %4, %12, off sc0 sc1\n\t"
      "global_load_dword %5, %13, off sc0 sc1\n\t"
      "global_load_dword %6, %14, off sc0 sc1\n\t"
      "global_load_dword %7, %15, off sc0 sc1\n\t"
      "s_waitcnt vmcnt(0)"
      : "=&v"(v0), "=&v"(v1), "=&v"(v2), "=&v"(v3),
        "=&v"(v4), "=&v"(v5), "=&v"(v6), "=&v"(v7)
      : "v"(b), "v"(b + 64), "v"(b + 128), "v"(b + 192),
        "v"(b + 256), "v"(b + 320), "v"(b + 384), "v"(b + 448)
      : "memory");
  return ((v0 + v1) + (v2 + v3)) + ((v4 + v5) + (v6 + v7));
}

// ---------------- weight re-layout: gate-interleaved Wx/Wh/bl + k-major Wp ----------------
__global__ __launch_bounds__(256) void prep_kernel(const float* __restrict__ Wx,
                                                   const float* __restrict__ Wh,
                                                   const float* __restrict__ bl,
                                                   const float* __restrict__ Wp,
                                                   float* __restrict__ ws) {
  float* WXI = ws + OFF_WXI;
  float* WHI = ws + OFF_WHI;
  float* BLI = ws + OFF_BLI;
  float* WPT = ws + OFF_WPT;
  const int t0 = 409 * 2048;
  const int t1 = t0 + 512 * 2048;
  const int t2 = t1 + 2048;
  const int total = t2 + 163840;
  for (int idx = blockIdx.x * blockDim.x + threadIdx.x; idx < total;
       idx += gridDim.x * blockDim.x) {
    if (idx < t0) {
      int k = idx >> 11, cc = idx & 2047;
      WXI[idx] = Wx[(size_t)k * 2048 + (cc & 3) * 512 + (cc >> 2)];
    } else if (idx < t1) {
      int j = idx - t0;
      int k = j >> 11, cc = j & 2047;
      WHI[j] = Wh[(size_t)k * 2048 + (cc & 3) * 512 + (cc >> 2)];
    } else if (idx < t2) {
      int cc = idx - t1;
      BLI[cc] = bl[(cc & 3) * 512 + (cc >> 2)];
    } else {
      // WPT[k4][j][ks] = Wp[k4*4+ks][j]
      int e = idx - t2;
      int k4 = e / 1280, r = e - k4 * 1280;
      int j = r >> 2, ks = r & 3;
      WPT[e] = Wp[(size_t)(k4 * 4 + ks) * 320 + j];
    }
  }
}

// ---------------- conv stack (validated) ----------------
__global__ __launch_bounds__(128) void conv_kernel(
    const float* __restrict__ img,
    const float* __restrict__ k1, const float* __restrict__ cb1, const float* __restrict__ g1,
    const float* __restrict__ be1, const float* __restrict__ mm1, const float* __restrict__ mv1,
    const float* __restrict__ k2, const float* __restrict__ cb2, const float* __restrict__ g2,
    const float* __restrict__ be2, const float* __restrict__ mm2, const float* __restrict__ mv2,
    const float* __restrict__ k3, const float* __restrict__ cb3, const float* __restrict__ g3,
    const float* __restrict__ be3, const float* __restrict__ mm3, const float* __restrict__ mv3,
    float* __restrict__ ws) {
  __shared__ float s_in[784];
  __shared__ float s_y1[13 * 13 * 8];
  __shared__ float s_y2[6 * 6 * 16];
  __shared__ float s_k1[72], s_k2[1152], s_k3[4608];
  __shared__ float s_s1[8], s_b1[8], s_s2[16], s_b2[16], s_s3[32], s_b3[32];
  float* FEATP = ws + OFF_FEATP;
  const int n = blockIdx.x, tid = threadIdx.x;
  const float* ip = img + (size_t)n * 784;
  for (int i = tid; i < 784; i += 128) s_in[i] = ip[i];
  for (int i = tid; i < 72; i += 128) s_k1[i] = k1[i];
  for (int i = tid; i < 1152; i += 128) s_k2[i] = k2[i];
  for (int i = tid; i < 4608; i += 128) s_k3[i] = k3[i];
  if (tid < 8) {
    float s = g1[tid] * rsqrtf(mv1[tid] + 1e-3f);
    s_s1[tid] = s; s_b1[tid] = (cb1[tid] - mm1[tid]) * s + be1[tid];
  } else if (tid >= 32 && tid < 48) {
    int c = tid - 32;
    float s = g2[c] * rsqrtf(mv2[c] + 1e-3f);
    s_s2[c] = s; s_b2[c] = (cb2[c] - mm2[c]) * s + be2[c];
  } else if (tid >= 64 && tid < 96) {
    int c = tid - 64;
    float s = g3[c] * rsqrtf(mv3[c] + 1e-3f);
    s_s3[c] = s; s_b3[c] = (cb3[c] - mm3[c]) * s + be3[c];
  }
  __syncthreads();
  for (int idx = tid; idx < 13 * 13 * 8; idx += 128) {
    int co = idx & 7, pos = idx >> 3;
    int j = pos % 13, i = pos / 13;
    float acc = 0.f;
    #pragma unroll
    for (int ky = 0; ky < 3; ++ky)
      #pragma unroll
      for (int kx = 0; kx < 3; ++kx)
        acc += s_in[(2 * i + ky) * 28 + (2 * j + kx)] * s_k1[(ky * 3 + kx) * 8 + co];
    float v = acc * s_s1[co] + s_b1[co];
    s_y1[idx] = v > 0.f ? v : 0.f;
  }
  __syncthreads();
  for (int idx = tid; idx < 6 * 6 * 16; idx += 128) {
    int co = idx & 15, pos = idx >> 4;
    int j = pos % 6, i = pos / 6;
    float acc = 0.f;
    for (int ky = 0; ky < 3; ++ky)
      for (int kx = 0; kx < 3; ++kx) {
        int base = ((2 * i + ky) * 13 + (2 * j + kx)) * 8;
        int kb = (ky * 3 + kx) * 128 + co;
        #pragma unroll
        for (int ci = 0; ci < 8; ++ci) acc += s_y1[base + ci] * s_k2[kb + ci * 16];
      }
    float v = acc * s_s2[co] + s_b2[co];
    s_y2[idx] = v > 0.f ? v : 0.f;
  }
  __syncthreads();
  for (int idx = tid; idx < 128; idx += 128) {
    int co = idx & 31, pos = idx >> 5;
    int j = pos & 1, i = pos >> 1;
    float acc = 0.f;
    for (int ky = 0; ky < 3; ++ky)
      for (int kx = 0; kx < 3; ++kx) {
        int base = ((2 * i + ky) * 6 + (2 * j + kx)) * 16;
        int kb = (ky * 3 + kx) * 512 + co;
        #pragma unroll
        for (int ci = 0; ci < 16; ++ci) acc += s_y2[base + ci] * s_k3[kb + ci * 32];
      }
    float v = acc * s_s3[co] + s_b3[co];
    FEATP[(size_t)n * 128 + idx] = v > 0.f ? v : 0.f;
  }
}

// ---------------- persistent LSTM scan: tagged-pair dataflow ----------------
// Roles: AZ 0-63 | AO 64-79 | ZH 80-143 (E64, K-halves) | OL 144-159 /
// OHI 160-175 | ATT 176-239 | WV 240-243 | COUT 244-251 | 252-255 idle.
// Epochs: h_t/rv_t/ZP_t/OH_t/WVP_t -> tag t+1; OUTPRE (AO step t) -> tag t.
// Zeroed buffers (tag 0) ARE the t=0 zero state.
// Spin-bandwidth discipline: critical spins (AZ, ATT-h, ZH, WVP) poll tight;
// slack-rich spins (OL/OHI, WV, AO, COUT) back off with s_sleep(8).
__global__ __launch_bounds__(512) void lstm_kernel(
    const int* __restrict__ labels,
    const float* __restrict__ Wo, const float* __restrict__ bo,
    const float* __restrict__ Wp, const float* __restrict__ bp,
    const float* __restrict__ Wf, const float* __restrict__ bf,
    float* __restrict__ ws, float* __restrict__ out) {
  extern __shared__ float dyn[];
  const float* FEATP = ws + OFF_FEATP;
  const float* WXI   = ws + OFF_WXI;
  const float* WHI   = ws + OFF_WHI;
  const float* BLI   = ws + OFF_BLI;
  float* ZP2A   = ws + OFF_ZP2A;
  float* ZP2B   = ws + OFF_ZP2B;
  float* OH2A   = ws + OFF_OH2A;
  float* OH2B   = ws + OFF_OH2B;
  float* OUTPRE2= ws + OFF_OUTPRE2;
  float* HT2    = ws + OFF_HT2;     // [2][512][32]p
  float* HTT2   = ws + OFF_HTT2;    // [2][32][512]p
  float* RVT2   = ws + OFF_RVT2;    // [2][256][32]p  (AZ readers)
  float* RVT2B  = ws + OFF_RVT2B;   // replica        (AO readers)
  float* WVP2   = ws + OFF_WVP2;    // [2][2][32][64]p
  const float* WPT = ws + OFF_WPT;  // [128][320][4]
  int*   BARp   = (int*)(ws + OFF_BAR);

  const int bid = blockIdx.x;
  const int tid = threadIdx.x;

  // cached WAR wait: skip the LLC poll when the cached read already covers it.
  int* bc = (int*)(dyn + 34808);
  auto waitC = [&](int base, int target, int& cache) {
    if (cache >= target) return;
    if (tid == 0) {
      int v = sum8_bar(BARp + base);
      while (v < target) v = sum8_bar(BARp + base);
      bc[base >> 9] = v;
    }
    __syncthreads();
    cache = bc[base >> 9];
    __syncthreads();
  };
  auto bumpC = [&](int base) {
    asm volatile("s_waitcnt vmcnt(0)" ::: "memory");
    __syncthreads();
    if (tid == 0) atomicAdd(&BARp[base + ((bid & 7) << 6)], 1);
  };

  // spin-stage an 8192-value pair buffer ([256][32]p) into [256][36]-padded LDS.
  // fast=true: critical-path consumer (tight poll); fast=false: slack consumer
  // (s_sleep(8) backoff -> ~4x less LLC spin traffic).
  auto stageP = [&](float* dst, const float* srcPairs, int tag, bool fast) {
    const iv4* sp = (const iv4*)srcPairs + tid;
    iv4 v[8];
    for (;;) {
      ld8i4_sc(sp, v);
      bool ok = true;
      #pragma unroll
      for (int j = 0; j < 8; ++j) ok = ok && (v[j][1] == tag) && (v[j][3] == tag);
      if (ok) break;
      if (fast) __builtin_amdgcn_s_sleep(2);
      else      __builtin_amdgcn_s_sleep(8);
    }
    #pragma unroll
    for (int j = 0; j < 8; ++j) {
      int i = (tid + j * 512) << 1;
      float2 f = {__int_as_float(v[j][0]), __int_as_float(v[j][2])};
      *(float2*)&dst[(i >> 5) * 36 + (i & 31)] = f;
    }
  };

  // ---- E32: Y[32c][32b] (validated). K mult of 16.
  auto E32 = [&](const float* Wm, const float* Am, int K, float* part, float2& r) {
    const int wv = tid >> 6, l = tid & 63;
    const int ksub = l & 1, cg = (l >> 1) & 3, bg = l >> 3;
    const int Kp = K >> 4;
    const int kb = wv * (K >> 3) + ksub * Kp;
    const float* wp = Wm + (size_t)kb * 32 + cg * 8;
    const float* ap = Am + (size_t)kb * 36 + bg * 4;
    float4 acc[8];
    #pragma unroll
    for (int i = 0; i < 8; ++i) acc[i] = {0.f, 0.f, 0.f, 0.f};
    #pragma unroll 4
    for (int kk = 0; kk < Kp; ++kk) {
      float4 w0 = *(const float4*)(wp + kk * 32);
      float4 w1 = *(const float4*)(wp + kk * 32 + 4);
      float4 a  = *(const float4*)(ap + kk * 36);
      float wl[8];
      *(float4*)&wl[0] = w0; *(float4*)&wl[4] = w1;
      #pragma unroll
      for (int i = 0; i < 8; ++i) {
        acc[i].x = fmaf(wl[i], a.x, acc[i].x);
        acc[i].y = fmaf(wl[i], a.y, acc[i].y);
        acc[i].z = fmaf(wl[i], a.z, acc[i].z);
        acc[i].w = fmaf(wl[i], a.w, acc[i].w);
      }
    }
    #pragma unroll
    for (int i = 0; i < 8; ++i) {
      acc[i].x += __shfl_xor(acc[i].x, 1, 64);
      acc[i].y += __shfl_xor(acc[i].y, 1, 64);
      acc[i].z += __shfl_xor(acc[i].z, 1, 64);
      acc[i].w += __shfl_xor(acc[i].w, 1, 64);
    }
    const int ob = (cg * 8) * 36 + bg * 4;
    if (ksub == 0 && wv < 4) {
      float* pb = part + wv * 1152 + ob;
      #pragma unroll
      for (int i = 0; i < 8; ++i) *(float4*)(pb + i * 36) = acc[i];
    }
    __syncthreads();
    if (ksub == 0 && wv >= 4) {
      float* pb = part + (wv - 4) * 1152 + ob;
      #pragma unroll
      for (int i = 0; i < 8; ++i) {
        float4 t = *(float4*)(pb + i * 36);
        t.x += acc[i].x; t.y += acc[i].y; t.z += acc[i].z; t.w += acc[i].w;
        *(float4*)(pb + i * 36) = t;
      }
    }
    __syncthreads();
    const int c = tid & 31, b2 = (tid >> 5) * 2;
    const int o = c * 36 + b2;
    float2 s0 = *(float2*)(part + o);
    float2 s1 = *(float2*)(part + 1152 + o);
    float2 s2 = *(float2*)(part + 2304 + o);
    float2 s3 = *(float2*)(part + 3456 + o);
    r.x = (s0.x + s1.x) + (s2.x + s3.x);
    r.y = (s0.y + s1.y) + (s2.y + s3.y);
  };

  // ---- E64: Y[64c][32b], K=256, rotated weight slab (validated).
  auto E64 = [&](const float* Wm, const float* Am, float* part, float4& r) {
    const int wv = tid >> 6, l = tid & 63;
    const int ksub = l & 1, cg = (l >> 1) & 7, bg = l >> 4;
    const int kb = wv * 32 + ksub * 16;
    const float* wp0 = Wm + (size_t)kb * 64 + ((cg * 8 + ksub * 4) & 63);
    const float* wp1 = Wm + (size_t)kb * 64 + ((cg * 8 + 4 + ksub * 4) & 63);
    const float* ap = Am + (size_t)kb * 36 + bg * 8;
    float4 acc[8][2];
    #pragma unroll
    for (int i = 0; i < 8; ++i) { acc[i][0] = {0.f,0.f,0.f,0.f}; acc[i][1] = {0.f,0.f,0.f,0.f}; }
    #pragma unroll 2
    for (int kk = 0; kk < 16; ++kk) {
      float4 w0 = *(const float4*)(wp0 + kk * 64);
      float4 w1 = *(const float4*)(wp1 + kk * 64);
      float4 a0 = *(const float4*)(ap + kk * 36);
      float4 a1 = *(const float4*)(ap + kk * 36 + 4);
      float wl[8];
      *(float4*)&wl[0] = w0; *(float4*)&wl[4] = w1;
      #pragma unroll
      for (int i = 0; i < 8; ++i) {
        acc[i][0].x = fmaf(wl[i], a0.x, acc[i][0].x);
        acc[i][0].y = fmaf(wl[i], a0.y, acc[i][0].y);
        acc[i][0].z = fmaf(wl[i], a0.z, acc[i][0].z);
        acc[i][0].w = fmaf(wl[i], a0.w, acc[i][0].w);
        acc[i][1].x = fmaf(wl[i], a1.x, acc[i][1].x);
        acc[i][1].y = fmaf(wl[i], a1.y, acc[i][1].y);
        acc[i][1].z = fmaf(wl[i], a1.z, acc[i][1].z);
        acc[i][1].w = fmaf(wl[i], a1.w, acc[i][1].w);
      }
    }
    #pragma unroll
    for (int i = 0; i < 8; ++i) {
      #pragma unroll
      for (int j = 0; j < 2; ++j) {
        acc[i][j].x += __shfl_xor(acc[i][j].x, 1, 64);
        acc[i][j].y += __shfl_xor(acc[i][j].y, 1, 64);
        acc[i][j].z += __shfl_xor(acc[i][j].z, 1, 64);
        acc[i][j].w += __shfl_xor(acc[i][j].w, 1, 64);
      }
    }
    const int ob = (cg * 8) * 36 + bg * 8;
    if (ksub == 0 && wv < 4) {
      float* pb = part + wv * 2304 + ob;
      #pragma unroll
      for (int i = 0; i < 8; ++i) {
        *(float4*)(pb + i * 36) = acc[i][0];
        *(float4*)(pb + i * 36 + 4) = acc[i][1];
      }
    }
    __syncthreads();
    if (ksub == 0 && wv >= 4) {
      float* pb = part + (wv - 4) * 2304 + ob;
      #pragma unroll
      for (int i = 0; i < 8; ++i) {
        float4 t0 = *(float4*)(pb + i * 36);
        float4 t1 = *(float4*)(pb + i * 36 + 4);
        t0.x += acc[i][0].x; t0.y += acc[i][0].y; t0.z += acc[i][0].z; t0.w += acc[i][0].w;
        t1.x += acc[i][1].x; t1.y += acc[i][1].y; t1.z += acc[i][1].z; t1.w += acc[i][1].w;
        *(float4*)(pb + i * 36) = t0;
        *(float4*)(pb + i * 36 + 4) = t1;
      }
    }
    __syncthreads();
    const int c = tid & 63, b4 = (tid >> 6) * 4;
    const int o = c * 36 + b4;
    float4 s0 = *(float4*)(part + o);
    float4 s1 = *(float4*)(part + 2304 + o);
    float4 s2 = *(float4*)(part + 4608 + o);
    float4 s3 = *(float4*)(part + 6912 + o);
    r.x = (s0.x + s1.x) + (s2.x + s3.x);
    r.y = (s0.y + s1.y) + (s2.y + s3.y);
    r.z = (s0.z + s1.z) + (s2.z + s3.z);
    r.w = (s0.w + s1.w) + (s2.w + s3.w);
  };

  // ---------------- one-time init: weights -> LDS ----------------
  if (bid < 64) {            // AZ: Wz (rv part of Wx) + Wxx (x part)
    const int c0 = bid * 32;
    for (int i = tid; i < 8192; i += 512)
      dyn[i] = WXI[(size_t)(153 + (i >> 5)) * 2048 + c0 + (i & 31)];
    for (int i = tid; i < 4096; i += 512)
      dyn[8192 + i] = WXI[(size_t)(i >> 5) * 2048 + c0 + (i & 31)];
    if (tid < 256) dyn[12288 + tid] = 0.f;  // Cst
  } else if (bid < 80) {     // AO: Wo rows 512..768
    const int u0 = (bid - 64) * 32;
    for (int i = tid; i < 8192; i += 512)
      dyn[i] = Wo[(size_t)(512 + (i >> 5)) * 512 + u0 + (i & 31)];
    if (tid < 32) dyn[8192 + tid] = bo[u0 + tid];
  } else if (bid < 144) {    // ZH: rotated E64 slab Wh[kh*256..+256][j0..j0+64]
    const int r = bid - 80;
    const int j0 = (r & 31) * 64, kh = r >> 5;
    for (int i = tid; i < 16384; i += 512) {
      int k = i >> 6, cc = i & 63;
      int cr = (cc + ((k >> 4) & 1) * 4) & 63;
      dyn[k * 64 + cr] = WHI[(size_t)(kh * 256 + k) * 2048 + j0 + cc];
    }
  } else if (bid < 160) {    // OL: Wo rows 0..256
    const int u0 = (bid - 144) * 32;
    for (int i = tid; i < 8192; i += 512)
      dyn[i] = Wo[(size_t)(i >> 5) * 512 + u0 + (i & 31)];
  } else if (bid < 176) {    // OHI: Wo rows 256..512
    const int u0 = (bid - 160) * 32;
    for (int i = tid; i < 8192; i += 512)
      dyn[i] = Wo[(size_t)(256 + (i >> 5)) * 512 + u0 + (i & 31)];
  } else if (bid < 240) {    // ATT: ring + cached norms + bias slices
    const int hp = (bid - 176) & 1;
    for (int i = tid; i < 17000; i += 512) dyn[i] = 0.f;            // ring[250][68]
    if (tid < 256) dyn[17000 + tid] = rsqrtf(1e-12f);               // rn
    if (tid < 128) dyn[21264 + tid] = bp[64 + hp * 128 + tid];      // bpk
    if (tid < 64)  dyn[21392 + tid] = bp[tid];                      // bpw
  } else if (bid < 244) {    // WV: Wp[kh*256..+256][cp*32..+32]
    const int kh = (bid - 240) >> 1, cp = (bid - 240) & 1;
    for (int i = tid; i < 8192; i += 512) {
      int k = i >> 5, c = i & 31;
      dyn[i] = Wp[(size_t)(kh * 256 + k) * 320 + cp * 32 + c];
    }
  } else if (bid < 252) {    // COUT: Wf + bf
    for (int i = tid; i < 12800; i += 512) dyn[i] = Wf[i];
    if (tid < 25) dyn[12800 + tid] = bf[tid];
  }
  __syncthreads();

  // ================= role bodies =================
  // AZ dyn: Wz[0,8192) Wxx[8192,12288) Cst[12288,12544) rvT[12544,21760)
  //         xT[21760,26368) zx[26368,27392) zf[27392,28416) part[28416,33024)
  // Combined spin: rv_{t-1} (8 iv4, tag t) + ZP_t A/B (2 iv4, tag t+1) in ONE
  // LLC round trip.
  auto azStage = [&](int t) {
    const float* rvP = RVT2 + ((t + 1) & 1) * 16384;
    const float* zaP = ZP2A + (t & 1) * 131072;
    const float* zbP = ZP2B + (t & 1) * 131072;
    float* rvT = dyn + 12544; float* zf = dyn + 27392;
    const int bb = tid >> 4, c2 = tid & 15;
    const iv4* rp = (const iv4*)rvP + tid;
    const size_t zi = (size_t)bb * 1024 + bid * 16 + c2;
    const iv4* za = (const iv4*)zaP + zi;
    const iv4* zb = (const iv4*)zbP + zi;
    iv4 v[10];
    for (;;) {
      ld10i4_sc(rp, za, zb, v);
      bool ok = true;
      #pragma unroll
      for (int j = 0; j < 8; ++j) ok = ok && (v[j][1] == t) && (v[j][3] == t);
      ok = ok && (v[8][1] == t + 1) && (v[8][3] == t + 1) &&
                 (v[9][1] == t + 1) && (v[9][3] == t + 1);
      if (ok) break;
      __builtin_amdgcn_s_sleep(1);
    }
    #pragma unroll
    for (int j = 0; j < 8; ++j) {
      int i = (tid + j * 512) << 1;
      float2 f = {__int_as_float(v[j][0]), __int_as_float(v[j][2])};
      *(float2*)&rvT[(i >> 5) * 36 + (i & 31)] = f;
    }
    float2 s = {__int_as_float(v[8][0]) + __int_as_float(v[9][0]),
                __int_as_float(v[8][2]) + __int_as_float(v[9][2])};
    *(float2*)&zf[bb * 32 + c2 * 2] = s;
  };
  auto azX = [&](int tt) {    // zx = x_{tt}@Wx, local
    float* Wxx = dyn + 8192; float* xT = dyn + 21760;
    float* zx = dyn + 26368; float* part = dyn + 28416;
    for (int i = tid; i < 4096; i += 512) {
      int b = i >> 7, k = i & 127;
      xT[k * 36 + b] = FEATP[((size_t)b * 250 + tt) * 128 + k];
    }
    __syncthreads();
    float2 r;
    E32(Wxx, xT, 128, part, r);
    const int c = tid & 31, b2 = (tid >> 5) * 2;
    zx[b2 * 32 + c] = r.x;
    zx[(b2 + 1) * 32 + c] = r.y;
  };
  // AO dyn: W[0,8192) bo[8192,8224) rvT[8224,17440) of[17440,18464) part[18464,23072)
  auto aoOut = [&](int t) {   // outpre_{t-1}: rv_{t-1} (tag t), OH_{t-1} (tag t)
    const int u0 = (bid - 64) * 32;
    const float* rvP  = RVT2B + ((t + 1) & 1) * 16384;   // replica B
    const float* ohaP = OH2A + ((t + 1) & 1) * 32768;
    const float* ohbP = OH2B + ((t + 1) & 1) * 32768;
    float* W = dyn; float* bo_l = dyn + 8192; float* rvT = dyn + 8224;
    float* of = dyn + 17440; float* part = dyn + 18464;
    {
      const int b = tid >> 4, c2 = tid & 15;
      const iv4* rp = (const iv4*)rvP + tid;
      const iv4* za = (const iv4*)ohaP + (b * 256 + (u0 >> 1) + c2);
      const iv4* zb = (const iv4*)ohbP + (b * 256 + (u0 >> 1) + c2);
      iv4 v[10];
      for (;;) {
        ld10i4_sc(rp, za, zb, v);
        bool ok = true;
        #pragma unroll
        for (int j = 0; j < 10; ++j) ok = ok && (v[j][1] == t) && (v[j][3] == t);
        if (ok) break;
        __builtin_amdgcn_s_sleep(8);
      }
      #pragma unroll
      for (int j = 0; j < 8; ++j) {
        int i = (tid + j * 512) << 1;
        float2 f = {__int_as_float(v[j][0]), __int_as_float(v[j][2])};
        *(float2*)&rvT[(i >> 5) * 36 + (i & 31)] = f;
      }
      float2 s = {__int_as_float(v[8][0]) + __int_as_float(v[9][0]),
                  __int_as_float(v[8][2]) + __int_as_float(v[9][2])};
      *(float2*)&of[b * 32 + c2 * 2] = s;
    }
    __syncthreads();
    float2 r;
    E32(W, rvT, 256, part, r);
    const int c = tid & 31, b2 = (tid >> 5) * 2;
    float bv = bo_l[c];
    st_pair(OUTPRE2, (size_t)b2 * 512 + u0 + c, r.x + of[b2 * 32 + c] + bv, t);
    st_pair(OUTPRE2, (size_t)(b2 + 1) * 512 + u0 + c, r.y + of[(b2 + 1) * 32 + c] + bv, t);
  };
  // OL/OHI dyn: W[0,8192) A[8192,17408) part[17408,22016)
  auto p2Gemm = [&](int t) {
    const float* htP = HT2 + (t & 1) * 32768;
    float* W = dyn; float* A = dyn + 8192; float* part = dyn + 17408;
    const bool isOLr = bid < 160;
    stageP(A, isOLr ? htP : (htP + 16384), t + 1, false);   // slack consumer
    __syncthreads();
    float2 r;
    E32(W, A, 256, part, r);
    const int c = tid & 31, b2 = (tid >> 5) * 2;
    const int u0 = (isOLr ? (bid - 144) : (bid - 160)) * 32;
    float* d = (isOLr ? OH2A : OH2B) + (t & 1) * 32768;
    st_pair(d, (size_t)b2 * 512 + u0 + c, r.x, t + 1);
    st_pair(d, (size_t)(b2 + 1) * 512 + u0 + c, r.y, t + 1);
  };

  // ---------------- dataflow role loops ----------------
  if (bid < 64) {                       // AZ
    int cCOH = 0;
    float* Wz = dyn; float* Cst = dyn + 12288; float* rvT = dyn + 12544;
    float* zx = dyn + 26368; float* zf = dyn + 27392; float* part = dyn + 28416;
    azX(0);
    for (int t = 0; t < 250; ++t) {
      azStage(t);                                // RAW ZP_t + rv_{t-1}, one RTT
      if (t >= 2) waitC(COH, 32 * (t - 1), cCOH);// HT WAR: OL/OHI_{t-2} read done
      __syncthreads();
      float2 r;
      E32(Wz, rvT, 256, part, r);
      const int c = tid & 31, b2 = (tid >> 5) * 2;
      zf[b2 * 32 + c] += r.x + zx[b2 * 32 + c];
      zf[(b2 + 1) * 32 + c] += r.y + zx[(b2 + 1) * 32 + c];
      __syncthreads();
      if (tid < 256) {
        int u = tid & 7, b = tid >> 3;
        float4 z = *(float4*)(zf + b * 32 + u * 4);
        float ig = sigm(z.x), fg = sigm(z.y), gg = tanhf(z.z), og = sigm(z.w);
        float cc = fg * Cst[b * 8 + u] + ig * gg;
        Cst[b * 8 + u] = cc;
        float hv = og * tanhf(cc);
        st_pair(HT2 + (t & 1) * 32768, (size_t)(bid * 8 + u) * 32 + b, hv, t + 1);
        st_pair(HTT2 + (t & 1) * 32768, (size_t)b * 512 + bid * 8 + u, hv, t + 1);
      }
      if (t < 249) azX(t + 1);
    }
  } else if (bid < 80) {                // AO
    int cCCO = 0;
    for (int t = 1; t <= 250; ++t) {
      if (t >= 2) waitC(CCO, 8 * (t - 1), cCCO); // OUTPRE WAR: COUT_{t-1} done
      aoOut(t);                                  // RAW rv/OH via tags
      bumpC(COP);
    }
  } else if (bid < 144) {               // ZH: E64 k-half partial of h@Wh
    const int r = bid - 80;
    const int j0 = (r & 31) * 64, kh = r >> 5;
    const int c = tid & 63, b4 = (tid >> 6) * 4;
    float* W = dyn; float* A = dyn + 16384; float* part = dyn + 25600;
    float* zpBase = kh ? ZP2B : ZP2A;
    const float blv = (kh == 0) ? BLI[j0 + c] : 0.f;
    for (int s = 0; s < 250; ++s) {
      float wx0 = 0.f, wx1 = 0.f, wx2 = 0.f, wx3 = 0.f;
      if (kh == 0) {     // label-row prefetch (input-dependent only)
        int l0 = labels[(b4 + 0) * 250 + s], l1 = labels[(b4 + 1) * 250 + s];
        int l2 = labels[(b4 + 2) * 250 + s], l3 = labels[(b4 + 3) * 250 + s];
        wx0 = WXI[(size_t)(128 + l0) * 2048 + j0 + c];
        wx1 = WXI[(size_t)(128 + l1) * 2048 + j0 + c];
        wx2 = WXI[(size_t)(128 + l2) * 2048 + j0 + c];
        wx3 = WXI[(size_t)(128 + l3) * 2048 + j0 + c];
      }
      stageP(A, HT2 + ((s + 1) & 1) * 32768 + kh * 16384, s, true);  // critical
      __syncthreads();
      float4 rr;
      E64(W, A, part, rr);
      float* zpD = zpBase + (s & 1) * 131072;
      st_pair(zpD, (size_t)(b4 + 0) * 2048 + j0 + c, rr.x + blv + wx0, s + 1);
      st_pair(zpD, (size_t)(b4 + 1) * 2048 + j0 + c, rr.y + blv + wx1, s + 1);
      st_pair(zpD, (size_t)(b4 + 2) * 2048 + j0 + c, rr.z + blv + wx2, s + 1);
      st_pair(zpD, (size_t)(b4 + 3) * 2048 + j0 + c, rr.w + blv + wx3, s + 1);
    }
  } else if (bid < 176) {               // OL / OHI
    int cCOP = 0;
    for (int t = 0; t < 250; ++t) {
      if (t >= 2) waitC(COP, 16 * (t - 1), cCOP);// OH WAR: AO_{t-1} read done
      p2Gemm(t);                                 // RAW h_t via tags
      bumpC(COH);
    }
  } else if (bid < 240) {               // ATT: keys + attention + rv
    float* ring = dyn;
    float* rn   = dyn + 17000;
    float* h_s  = dyn + 17256;
    float* kpart= dyn + 17768;
    float* kn   = dyn + 18408;
    float* att  = dyn + 18536;
    float* redS = dyn + 19068;
    float* pslab= dyn + 19088;
    float* bpk  = dyn + 21264;
    float* bpw  = dyn + 21392;
    const int b = (bid - 176) >> 1, hp = (bid - 176) & 1;
    const int j = tid & 127, q = tid >> 7;
    const int J = 64 + hp * 128 + j;
    const fv4* wbase = (const fv4*)WPT + q * 32 * 320 + J;
    int cCOP = 0;
    for (int t = 0; t < 250; ++t) {
      // prefetch HALF this thread's Wp chunk; keep-alive asm pins the loads
      // BEFORE the spin so the compiler cannot sink them past it.
      fv4 pf[16];
      #pragma unroll
      for (int i = 0; i < 16; ++i) pf[i] = wbase[i * 320];
      asm volatile("" :: "v"(pf[0]), "v"(pf[1]), "v"(pf[2]), "v"(pf[3]),
                         "v"(pf[4]), "v"(pf[5]), "v"(pf[6]), "v"(pf[7]),
                         "v"(pf[8]), "v"(pf[9]), "v"(pf[10]), "v"(pf[11]),
                         "v"(pf[12]), "v"(pf[13]), "v"(pf[14]), "v"(pf[15]));
      if (t >= 2) waitC(COP, 16 * (t - 1), cCOP);// RVT WAR: AO_{t-1} read done
      h_s[tid] = spin_pair(HTT2 + (t & 1) * 32768, (size_t)b * 512 + tid, t + 1);
      __syncthreads();
      {  // key GEMM: half from registers, half streamed from L2/LLC
        float a = 0.f;
        #pragma unroll
        for (int i = 0; i < 16; ++i) {
          fv4 h4 = *(const fv4*)&h_s[q * 128 + i * 4];
          a += pf[i].x * h4.x + pf[i].y * h4.y + pf[i].z * h4.z + pf[i].w * h4.w;
        }
        #pragma unroll 4
        for (int i = 16; i < 32; ++i) {
          fv4 w4 = wbase[i * 320];
          fv4 h4 = *(const fv4*)&h_s[q * 128 + i * 4];
          a += w4.x * h4.x + w4.y * h4.y + w4.z * h4.z + w4.w * h4.w;
        }
        kpart[q * 128 + j] = a;
      }
      __syncthreads();
      if (tid < 128) {  // fused reduce + tanh + per-head L2 norm (wave-local)
        float kr = kpart[tid] + kpart[128 + tid] + kpart[256 + tid] +
                   kpart[384 + tid] + bpk[tid];
        float v = tanhf(kr);
        float pq = v * v;
        #pragma unroll
        for (int off = 32; off; off >>= 1) pq += __shfl_xor(pq, off, 64);
        kn[tid] = v * rsqrtf(fmaxf(pq, 1e-12f));
      }
      __syncthreads();
      const int start = 250 - t;          // live cells: m < t at p = start+m (no wrap)
      const int m = tid >> 1, hh = tid & 1;
      {  // dots + exp. Dead cells (t <= m < 250) are zero vectors -> e = 1
         // exactly (cosine score 0), no dot needed.
        float e = 0.f;
        if (m < t) {
          const float4* c4 = (const float4*)ring + (start + m) * 17;
          const float4* k4 = (const float4*)kn + hh * 16;
          float d = 0.f;
          #pragma unroll
          for (int s4 = 0; s4 < 16; ++s4) {
            float4 cc = c4[s4], kk = k4[s4];
            d += cc.x * kk.x + cc.y * kk.y + cc.z * kk.z + cc.w * kk.w;
          }
          e = __expf(d * rn[start + m]);
          att[hh * 256 + m] = e;
        } else if (m < 250) {
          e = 1.f;
        }
        float sm = e;
        #pragma unroll
        for (int off = 2; off <= 32; off <<= 1) sm += __shfl_xor(sm, off, 64);
        if ((tid & 63) < 2) redS[(tid >> 6) * 2 + (tid & 1)] = sm;
      }
      __syncthreads();
      {  // weighted sum over LIVE cells only (dead cells contribute 0)
        int hh2 = tid >> 8, s4 = (tid >> 4) & 15, g = tid & 15;
        float4 a4 = {0.f, 0.f, 0.f, 0.f};
        for (int mm = g; mm < t; mm += 16) {
          float w = att[hh2 * 256 + mm];
          float4 cc = ((const float4*)ring)[(start + mm) * 17 + s4];
          a4.x = fmaf(w, cc.x, a4.x); a4.y = fmaf(w, cc.y, a4.y);
          a4.z = fmaf(w, cc.z, a4.z); a4.w = fmaf(w, cc.w, a4.w);
        }
        *(float4*)&pslab[(hh2 * 16 + s4) * 68 + g * 4] = a4;
      }
      __syncthreads();
      if (tid < 128) {
        int hh3 = tid >> 6, s = tid & 63;
        float denom = redS[hh3];
        #pragma unroll
        for (int w = 1; w < 8; ++w) denom += redS[w * 2 + hh3];
        float sum = 0.f;
        #pragma unroll
        for (int g = 0; g < 16; ++g)
          sum += pslab[(hh3 * 16 + (s >> 2)) * 68 + g * 4 + (s & 3)];
        float rvv = sum / denom;
        size_t ri = (size_t)((2 * hp + hh3) * 64 + s) * 32 + b;
        st_pair(RVT2 + (t & 1) * 16384, ri, rvv, t + 1);
        st_pair(RVT2B + (t & 1) * 16384, ri, rvv, t + 1);
      }
      __syncthreads();                            // ring readers done before update
      {  // ring update with wv_t (tags; off critical path)
        const int ip = 249 - t;
        if (tid < 64) {
          float2 p01 = spin_pair_2addr(
              WVP2 + (t & 1) * 8192 + 2 * ((size_t)b * 64 + tid),
              WVP2 + (t & 1) * 8192 + 4096 + 2 * ((size_t)b * 64 + tid), t + 1);
          float nv = tanhf(p01.x + p01.y + bpw[tid]);
          ring[ip * 68 + tid] = nv;
          float n2 = nv * nv;
          #pragma unroll
          for (int off = 32; off; off >>= 1) n2 += __shfl_xor(n2, off, 64);
          if (tid == 0) rn[ip] = rsqrtf(fmaxf(n2, 1e-12f));
        }
      }
      bumpC(CRING);
    }
  } else if (bid < 244) {               // WV: wv partials
    // dyn: W[0,8192) A[8192,17408) part[17408,22016)
    const int kh = (bid - 240) >> 1, cp = (bid - 240) & 1;
    float* W = dyn; float* A = dyn + 8192; float* part = dyn + 17408;
    int cCR = 0;
    for (int t = 0; t < 250; ++t) {
      if (t >= 2) waitC(CRING, 64 * (t - 1), cCR);// WVP WAR: ring-update done
      stageP(A, HT2 + (t & 1) * 32768 + kh * 16384, t + 1, false);  // slack
      __syncthreads();
      float2 r;
      E32(W, A, 256, part, r);
      const int c = tid & 31, b2 = (tid >> 5) * 2;
      float* d = WVP2 + (t & 1) * 8192 + kh * 4096;
      st_pair(d, (size_t)b2 * 64 + cp * 32 + c, r.x, t + 1);
      st_pair(d, (size_t)(b2 + 1) * 64 + cp * 32 + c, r.y, t + 1);
    }
  } else if (bid < 252) {               // COUT: 4 batches, one quad spin per step
    const int b0 = (bid - 244) * 4;
    float* WfL = dyn; float* bfL = dyn + 12800;
    float* to4 = dyn + 12832;           // [4][512]
    float* lp  = dyn + 14880;           // [400]
    float* lg  = dyn + 15280;           // [27]
    for (int t = 1; t <= 250; ++t) {
      {
        const iv2* p0 = (const iv2*)(OUTPRE2 + 2 * ((size_t)(b0 + 0) * 512 + tid));
        const iv2* p1 = (const iv2*)(OUTPRE2 + 2 * ((size_t)(b0 + 1) * 512 + tid));
        const iv2* p2 = (const iv2*)(OUTPRE2 + 2 * ((size_t)(b0 + 2) * 512 + tid));
        const iv2* p3 = (const iv2*)(OUTPRE2 + 2 * ((size_t)(b0 + 3) * 512 + tid));
        iv2 v0, v1, v2, v3;
        for (;;) {
          ld4x2_sc(p0, p1, p2, p3, v0, v1, v2, v3);
          if (v0[1] == t && v1[1] == t && v2[1] == t && v3[1] == t) break;
          __builtin_amdgcn_s_sleep(8);
        }
        to4[tid]        = tanhf(__int_as_float(v0[0]));
        to4[512 + tid]  = tanhf(__int_as_float(v1[0]));
        to4[1024 + tid] = tanhf(__int_as_float(v2[0]));
        to4[1536 + tid] = tanhf(__int_as_float(v3[0]));
      }
      __syncthreads();
      for (int i = 0; i < 4; ++i) {
        float* to = to4 + i * 512;
        if (tid < 400) {
          int l = tid % 25, p = tid / 25;
          float s = 0.f;
          #pragma unroll
          for (int q = 0; q < 32; ++q) { int k = p * 32 + q; s += to[k] * WfL[k * 25 + l]; }
          lp[p * 25 + l] = s;
        }
        __syncthreads();
        if (tid < 25) {
          float s = bfL[tid];
          #pragma unroll
          for (int p = 0; p < 16; ++p) s += lp[p * 25 + tid];
          lg[tid] = s;
        }
        __syncthreads();
        if (tid == 0) {
          float mx = lg[0];
          for (int l = 1; l < 25; ++l) mx = fmaxf(mx, lg[l]);
          float ss = 0.f;
          for (int l = 0; l < 25; ++l) ss += __expf(lg[l] - mx);
          lg[25] = mx; lg[26] = 1.f / ss;
        }
        __syncthreads();
        if (tid < 25)
          out[((size_t)(b0 + i) * 250 + (t - 1)) * 25 + tid] =
              __expf(lg[tid] - lg[25]) * lg[26];
        __syncthreads();
      }
      bumpC(CCO);
    }
  }
}

extern "C" void kernel_launch(void* const* d_in, const int* in_sizes, int n_in,
                              void* d_out, int out_size, void* d_ws, size_t ws_size,
                              hipStream_t stream) {
  const float* images = (const float*)d_in[0];
  const int* labels = (const int*)d_in[1];
  const float* k1  = (const float*)d_in[2];
  const float* cb1 = (const float*)d_in[3];
  const float* g1  = (const float*)d_in[4];
  const float* be1 = (const float*)d_in[5];
  const float* mm1 = (const float*)d_in[6];
  const float* mv1 = (const float*)d_in[7];
  const float* k2  = (const float*)d_in[8];
  const float* cb2 = (const float*)d_in[9];
  const float* g2  = (const float*)d_in[10];
  const float* be2 = (const float*)d_in[11];
  const float* mm2 = (const float*)d_in[12];
  const float* mv2 = (const float*)d_in[13];
  const float* k3  = (const float*)d_in[14];
  const float* cb3 = (const float*)d_in[15];
  const float* g3  = (const float*)d_in[16];
  const float* be3 = (const float*)d_in[17];
  const float* mm3 = (const float*)d_in[18];
  const float* mv3 = (const float*)d_in[19];
  const float* Wx  = (const float*)d_in[20];
  const float* Wh  = (const float*)d_in[21];
  const float* bl  = (const float*)d_in[22];
  const float* Wp  = (const float*)d_in[23];
  const float* bp  = (const float*)d_in[24];
  const float* Wo  = (const float*)d_in[25];
  const float* bo  = (const float*)d_in[26];
  const float* Wf  = (const float*)d_in[27];
  const float* bf  = (const float*)d_in[28];
  float* ws = (float*)d_ws;

  hipFuncSetAttribute((const void*)lstm_kernel,
                      hipFuncAttributeMaxDynamicSharedMemorySize, DYN_BYTES);

  // zero all pair buffers + counters (tags -> 0 = step-0 zero state)
  hipMemsetAsync((char*)d_ws + OFF_ZP2A * sizeof(float), 0,
                 (OFF_WPT - OFF_ZP2A) * sizeof(float), stream);
  prep_kernel<<<1024, 256, 0, stream>>>(Wx, Wh, bl, Wp, ws);
  conv_kernel<<<8000, 128, 0, stream>>>(images,
      k1, cb1, g1, be1, mm1, mv1,
      k2, cb2, g2, be2, mm2, mv2,
      k3, cb3, g3, be3, mm3, mv3, ws);
  lstm_kernel<<<256, 512, DYN_BYTES, stream>>>(labels, Wo, bo, Wp, bp, Wf, bf, ws,
                                               (float*)d_out);
}